// Round 12
// baseline (1002.026 us; speedup 1.0000x reference)
//
#include <hip/hip_runtime.h>
#include <stdint.h>

typedef unsigned short u16;
typedef unsigned int   u32;
typedef __bf16  bf16x8 __attribute__((ext_vector_type(8)));
typedef float   f32x4  __attribute__((ext_vector_type(4)));

#define LORA_SCALE 2.0f
#define QSCALE 0.08838834764831845f   // 1/sqrt(128)
#define LOG2E  1.4426950408889634f
#define RESCALE_THR 8.0f

__device__ __forceinline__ u16 f2bf(float f){
  u32 u = __builtin_bit_cast(u32, f);
  u32 r = (u + 0x7fffu + ((u >> 16) & 1u)) >> 16;   // RNE
  return (u16)r;
}
__device__ __forceinline__ float bf2f(u16 v){
  return __builtin_bit_cast(float, ((u32)v) << 16);
}
// pack 2 f32 -> 2 bf16 in one VALU op (no builtin on gfx950; T12 recipe)
__device__ __forceinline__ u32 cvt_pk_bf16(float lo, float hi){
  u32 d;
  asm("v_cvt_pk_bf16_f32 %0, %1, %2" : "=v"(d) : "v"(lo), "v"(hi));
  return d;
}

typedef __attribute__((address_space(3))) u32 lds_u32_t;
typedef __attribute__((address_space(1))) const u32 g_u32_t;

// async global->LDS, 16B per lane; LDS dest = wave-uniform base + lane*16
__device__ __forceinline__ void gload16(const void* g, void* l){
  __builtin_amdgcn_global_load_lds((g_u32_t*)(unsigned long long)g,
                                   (lds_u32_t*)(u32)(unsigned long long)l,
                                   16, 0, 0);
}

// ---------------- 4x W fp32 -> bf16 convert, one launch ----------------
__global__ __launch_bounds__(256) void cvt_w4(const float* __restrict__ W0,
    const float* __restrict__ W1, const float* __restrict__ W2,
    const float* __restrict__ W3, u16* __restrict__ wqkv, u16* __restrict__ wo){
  int sel = blockIdx.x >> 11;
  int inner = blockIdx.x & 2047;
  const float* src = sel==0 ? W0 : sel==1 ? W1 : sel==2 ? W2 : W3;
  u16* dst = sel<3 ? (wqkv + (size_t)sel*4194304) : wo;
  int i = (inner*256 + threadIdx.x) * 8;
  float4 a = *(const float4*)(src + i);
  float4 b = *(const float4*)(src + i + 4);
  u16 o[8] = {f2bf(a.x),f2bf(a.y),f2bf(a.z),f2bf(a.w),
              f2bf(b.x),f2bf(b.y),f2bf(b.z),f2bf(b.w)};
  *(uint4*)(dst + i) = *(const uint4*)o;
}

// ---------------- fused: x fp32 -> xbf bf16 AND xa[m][r] for 3 A's (1 row/wave) ----------------
__global__ __launch_bounds__(256) void lora_x_fused(const float* __restrict__ x,
    const float* __restrict__ A0, const float* __restrict__ A1, const float* __restrict__ A2,
    float* __restrict__ xout, u16* __restrict__ xbf){
  int w = threadIdx.x >> 6, lane = threadIdx.x & 63;
  int m = blockIdx.x * 4 + w;
  float acc[3][8];
  #pragma unroll
  for (int g=0; g<3; ++g)
    #pragma unroll
    for (int r=0; r<8; ++r) acc[g][r] = 0.f;
  const float* As[3] = {A0, A1, A2};
  #pragma unroll 1
  for (int it=0; it<8; ++it){
    int k = it*256 + lane*4;
    float4 xv = *(const float4*)(x + (size_t)m*2048 + k);
    u16 o[4] = {f2bf(xv.x), f2bf(xv.y), f2bf(xv.z), f2bf(xv.w)};
    *(uint2*)(xbf + (size_t)m*2048 + k) = *(const uint2*)o;
    #pragma unroll
    for (int g=0; g<3; ++g){
      const float* Ag = As[g];
      #pragma unroll
      for (int r=0; r<8; ++r){
        float4 av = *(const float4*)(Ag + r*2048 + k);
        acc[g][r] += xv.x*av.x + xv.y*av.y + xv.z*av.z + xv.w*av.w;
      }
    }
  }
  #pragma unroll
  for (int g=0; g<3; ++g)
    #pragma unroll
    for (int r=0; r<8; ++r){
      float v = acc[g][r];
      #pragma unroll
      for (int off=32; off; off>>=1) v += __shfl_xor(v, off);
      if (lane == 0) xout[g*32768 + m*8 + r] = v;
    }
}

// ---------------- LoRA stage 1 (ctx bf16 path, 1 row/wave) ----------------
__global__ __launch_bounds__(256) void lora_xa_bf16(const u16* __restrict__ xin,
    const float* __restrict__ A0, float* __restrict__ xout){
  int w = threadIdx.x >> 6, lane = threadIdx.x & 63;
  int m = blockIdx.x * 4 + w;
  float acc[8];
  #pragma unroll
  for (int r=0; r<8; ++r) acc[r] = 0.f;
  #pragma unroll 1
  for (int it=0; it<8; ++it){
    int k = it*256 + lane*4;
    ushort4 u = *(const ushort4*)(xin + (size_t)m*2048 + k);
    float4 xv = {bf2f(u.x), bf2f(u.y), bf2f(u.z), bf2f(u.w)};
    #pragma unroll
    for (int r=0; r<8; ++r){
      float4 av = *(const float4*)(A0 + r*2048 + k);
      acc[r] += xv.x*av.x + xv.y*av.y + xv.z*av.z + xv.w*av.w;
    }
  }
  #pragma unroll
  for (int r=0; r<8; ++r){
    float v = acc[r];
    #pragma unroll
    for (int off=32; off; off>>=1) v += __shfl_xor(v, off);
    if (lane == 0) xout[m*8 + r] = v;
  }
}

// ---------------- GEMM core v12: v7 geometry, 2 LDS buffers (48KB) -> 3 blocks/CU ----------------
// BM=256 BN=128 BK=32, 4 waves 2Mx2N, per-wave 128x64. Double-buffered LDS (2 x 24KB).
// Per K-step t: issue stage(t+1) into buf[(t+1)&1]; ds_read+MFMA from buf[t&1];
// vmcnt(0) (own 6 loads) + barrier. The drain stall of one block hides under the
// other 2 co-resident blocks' MFMA (m114 wave-level overlap); 768 blocks = exactly
// 3/CU x 256 CU = ONE round, zero tail idle (was 2 rounds at 72KB/2 blocks).
// T2 swizzle (verified 0-conflict): LDS 16B-slot s at row r holds global slot s^((r>>1)&3).
__device__ __forceinline__ void gemm_core_v12(
    const u16* __restrict__ Aptr,   // + m0*2048 (256 rows)
    const u16* __restrict__ Wptr,   // + n0g*2048 (128 rows)
    u16* lds, int tid, f32x4 acc[8][4]){
  const int Kd = 2048;
  int l = tid & 63, w = tid >> 6;
  int l15 = l & 15, l4 = l >> 4;
  int wm = w >> 1, wn = w & 1;
  char* L = (char*)lds;
  int wb = w * 1024;
  const u16* asrc[4]; const u16* bsrc[2];
  #pragma unroll
  for (int i=0;i<4;i++){ int row=(i*4+w)*16+(l>>2); int sc=((l&3)^((row>>1)&3))<<3;
    asrc[i] = Aptr + (size_t)row*Kd + sc; }
  #pragma unroll
  for (int i=0;i<2;i++){ int row=(i*4+w)*16+(l>>2); int sc=((l&3)^((row>>1)&3))<<3;
    bsrc[i] = Wptr + (size_t)row*Kd + sc; }
  int aoff[8], boff[4];
  #pragma unroll
  for (int mr=0;mr<8;mr++){ int ra=wm*128+mr*16+l15; aoff[mr]=ra*64+((l4^((ra>>1)&3))<<4); }
  #pragma unroll
  for (int nr=0;nr<4;nr++){ int rb=wn*64+nr*16+l15; boff[nr]=16384+rb*64+((l4^((rb>>1)&3))<<4); }

  auto STG = [&](int kt, int sbase){
    char* D = L + sbase;
    gload16(asrc[0]+kt, D +        wb);
    gload16(asrc[1]+kt, D +  4096+ wb);
    gload16(asrc[2]+kt, D +  8192+ wb);
    gload16(asrc[3]+kt, D + 12288+ wb);
    gload16(bsrc[0]+kt, D + 16384+ wb);
    gload16(bsrc[1]+kt, D + 20480+ wb);
  };

  STG(0, 0);
  asm volatile("s_waitcnt vmcnt(0)" ::: "memory");   // K-step 0 resident
  __builtin_amdgcn_s_barrier();

  int bb = 0, sb = 24576, kt2 = 32;
  #pragma unroll 1
  for (int t = 0; t < 64; ++t){
    if (t < 63) STG(kt2, sb);            // issue early: latency hides under this step's MFMA
    bf16x8 af[4], ag[4], bf[4];
    #pragma unroll
    for (int nr=0;nr<4;nr++) bf[nr] = *(const bf16x8*)(L + bb + boff[nr]);
    #pragma unroll
    for (int mr=0;mr<4;mr++) af[mr] = *(const bf16x8*)(L + bb + aoff[mr]);
    #pragma unroll
    for (int mr=0;mr<4;mr++) ag[mr] = *(const bf16x8*)(L + bb + aoff[mr+4]);
    __builtin_amdgcn_s_setprio(1);
    #pragma unroll
    for (int mr=0;mr<4;mr++)
      #pragma unroll
      for (int nr=0;nr<4;nr++)
        acc[mr][nr] = __builtin_amdgcn_mfma_f32_16x16x32_bf16(af[mr], bf[nr], acc[mr][nr], 0,0,0);
    #pragma unroll
    for (int mr=0;mr<4;mr++)
      #pragma unroll
      for (int nr=0;nr<4;nr++)
        acc[mr+4][nr] = __builtin_amdgcn_mfma_f32_16x16x32_bf16(ag[mr], bf[nr], acc[mr+4][nr], 0,0,0);
    __builtin_amdgcn_s_setprio(0);
    if (t < 63){
      asm volatile("s_waitcnt vmcnt(0)" ::: "memory");   // t+1 resident
      __builtin_amdgcn_s_barrier();
    }
    bb ^= 24576; sb ^= 24576; kt2 += 32;
  }
}

// ---------------- fused QKV GEMM (256x128 tiles, 768 blocks, 4 waves, 3 blocks/CU) ----------------
// XCD map: XCD x owns mt {2x,2x+1} x all 48 nt -> A-slab L2-resident.
// V blocks write Vt directly (LDS transpose epilogue, split into two 32KB halves).
__global__ __launch_bounds__(256, 3) void gemm_qkv(
    const u16* __restrict__ A, const u16* __restrict__ W,
    const float* __restrict__ bq, const float* __restrict__ bk, const float* __restrict__ bv,
    const float* __restrict__ lBq, const float* __restrict__ lBk, const float* __restrict__ lBv,
    const float* __restrict__ xa, u16* __restrict__ Qb, u16* __restrict__ Kb, u16* __restrict__ Vtb){
  __shared__ u16 lds[24576];   // 48 KB: 2 bufs x 24 KB (V-epilogue reuses 32 KB, 2 halves)
  int tid = threadIdx.x;
  int l = tid & 63, w = tid >> 6;
  int l15 = l & 15, l4 = l >> 4;
  int wm = w >> 1, wn = w & 1;
  int bid = blockIdx.x;
  int xcd = bid & 7, local = bid >> 3;           // local 0..95
  int mt = xcd*2 + (local >= 48);
  int nt = (local < 48) ? local : local - 48;
  int m0 = mt * 256, n0g = nt * 128;
  int which = nt >> 4;                            // 0=q 1=k 2=v
  int n0 = (nt & 15) * 128;
  const float* bias = which==0 ? bq : which==1 ? bk : bv;
  const float* lB   = which==0 ? lBq : which==1 ? lBk : lBv;
  const float* xs   = xa + which*32768;

  f32x4 acc[8][4];
  #pragma unroll
  for (int mr=0; mr<8; mr++)
    #pragma unroll
    for (int nr=0; nr<4; nr++) acc[mr][nr] = (f32x4){0.f,0.f,0.f,0.f};

  gemm_core_v12(A + (size_t)m0*2048, W + (size_t)n0g*2048, lds, tid, acc);

  float bvv[4]; float4 lb0[4], lb1[4];
  #pragma unroll
  for (int nr=0; nr<4; nr++){
    int col = n0 + wn*64 + nr*16 + l15;
    bvv[nr] = bias[col];
    lb0[nr] = *(const float4*)(lB + col*8);
    lb1[nr] = *(const float4*)(lB + col*8 + 4);
  }

  if (which == 2){
    // ---- V: transpose through LDS in two 128-row halves, write Vt[bh][d][s] kv-swizzled ----
    char* L = (char*)lds;
    int bq_ = m0 >> 11, s0 = m0 & 2047, h = n0 >> 7;
    u16* vt = Vtb + ((size_t)((bq_*16 + h)*128)) * 2048;
    #pragma unroll
    for (int hh = 0; hh < 2; ++hh){
      __syncthreads();   // prior half's reads (or core's last LDS reads) done
      if (wm == hh){
        #pragma unroll
        for (int mr=0; mr<8; mr++){
          float vv[4][4];   // [nr][j]
          #pragma unroll
          for (int j=0; j<4; j++){
            int r = m0 + wm*128 + mr*16 + l4*4 + j;
            float4 xv0 = *(const float4*)(xs + (size_t)r*8);
            float4 xv1 = *(const float4*)(xs + (size_t)r*8 + 4);
            #pragma unroll
            for (int nr=0; nr<4; nr++)
              vv[nr][j] = acc[mr][nr][j] + bvv[nr] + LORA_SCALE * (
                  xv0.x*lb0[nr].x + xv0.y*lb0[nr].y + xv0.z*lb0[nr].z + xv0.w*lb0[nr].w +
                  xv1.x*lb1[nr].x + xv1.y*lb1[nr].y + xv1.z*lb1[nr].z + xv1.w*lb1[nr].w);
          }
          int s_ = mr*16 + l4*4;           // local row within half (0..127)
          #pragma unroll
          for (int nr=0; nr<4; nr++){
            int d = wn*64 + nr*16 + l15;
            uint2 pk = {cvt_pk_bf16(vv[nr][0], vv[nr][1]), cvt_pk_bf16(vv[nr][2], vv[nr][3])};
            *(uint2*)(L + d*256 + ((s_*2) ^ ((d & 15) << 4))) = pk;
          }
        }
      }
      __syncthreads();
      #pragma unroll
      for (int i=0; i<8; ++i){
        int flat = i*4096 + tid*16;
        int d = flat >> 8, s2 = flat & 255;
        uint4 val = *(const uint4*)(L + d*256 + (s2 ^ ((d & 15) << 4)));
        int sa = s0 + hh*128 + (s2 >> 1);
        *(uint4*)(vt + (size_t)d*2048 + (sa & ~63) + ((sa & 63) ^ ((d & 7) << 3))) = val;
      }
    }
    return;
  }

  // ---- Q/K: swizzled bf16 store ----
  u16* outp = (which == 0) ? Qb : Kb;
  float oscale = (which == 0) ? QSCALE*LOG2E : 1.0f;
  #pragma unroll
  for (int mr=0; mr<8; mr++)
    #pragma unroll
    for (int j=0; j<4; j++){
      int r = m0 + wm*128 + mr*16 + l4*4 + j;
      float4 xv0 = *(const float4*)(xs + (size_t)r*8);
      float4 xv1 = *(const float4*)(xs + (size_t)r*8 + 4);
      #pragma unroll
      for (int nr=0; nr<4; nr++){
        int col = n0 + wn*64 + nr*16 + l15;
        float v = acc[mr][nr][j] + bvv[nr] + LORA_SCALE * (
            xv0.x*lb0[nr].x + xv0.y*lb0[nr].y + xv0.z*lb0[nr].z + xv0.w*lb0[nr].w +
            xv1.x*lb1[nr].x + xv1.y*lb1[nr].y + xv1.z*lb1[nr].z + xv1.w*lb1[nr].w);
        v *= oscale;
        int cs = col ^ ((r & 7) << 3);
        outp[(size_t)r*2048 + cs] = f2bf(v);
      }
    }
}

// ---------------- O projection GEMM (256x128 tiles, 256 blocks, fp32 out) ----------------
__global__ __launch_bounds__(256, 3) void gemm_o(
    const u16* __restrict__ A, const u16* __restrict__ W,
    const float* __restrict__ bias, const float* __restrict__ lB,
    const float* __restrict__ xa, float* __restrict__ outp){
  __shared__ u16 lds[24576];   // 48 KB
  int tid = threadIdx.x;
  int l = tid & 63, w = tid >> 6;
  int l15 = l & 15, l4 = l >> 4;
  int wm = w >> 1, wn = w & 1;
  int bid = blockIdx.x;
  int xcd = bid & 7, local = bid >> 3;           // local 0..31
  int mt = xcd*2 + (local >= 16);
  int nt = local & 15;
  int m0 = mt * 256, n0 = nt * 128;

  f32x4 acc[8][4];
  #pragma unroll
  for (int mr=0; mr<8; mr++)
    #pragma unroll
    for (int nr=0; nr<4; nr++) acc[mr][nr] = (f32x4){0.f,0.f,0.f,0.f};

  gemm_core_v12(A + (size_t)m0*2048, W + (size_t)n0*2048, lds, tid, acc);

  float bv[4]; float4 lb0[4], lb1[4];
  #pragma unroll
  for (int nr=0; nr<4; nr++){
    int col = n0 + wn*64 + nr*16 + l15;
    bv[nr] = bias[col];
    lb0[nr] = *(const float4*)(lB + col*8);
    lb1[nr] = *(const float4*)(lB + col*8 + 4);
  }
  #pragma unroll
  for (int mr=0; mr<8; mr++)
    #pragma unroll
    for (int j=0; j<4; j++){
      int r = m0 + wm*128 + mr*16 + l4*4 + j;
      float4 xv0 = *(const float4*)(xa + (size_t)r*8);
      float4 xv1 = *(const float4*)(xa + (size_t)r*8 + 4);
      #pragma unroll
      for (int nr=0; nr<4; nr++){
        int col = n0 + wn*64 + nr*16 + l15;
        float v = acc[mr][nr][j] + bv[nr] + LORA_SCALE * (
            xv0.x*lb0[nr].x + xv0.y*lb0[nr].y + xv0.z*lb0[nr].z + xv0.w*lb0[nr].w +
            xv1.x*lb1[nr].x + xv1.y*lb1[nr].y + xv1.z*lb1[nr].z + xv1.w*lb1[nr].w);
        outp[(size_t)r*2048 + col] = v;
      }
    }
}

// ---------------- flash attention: QBLK=128, KVBLK=64, 4 waves x 32 q-rows ----------------
__global__ __launch_bounds__(256, 2) void attn_kernel(
    const u16* __restrict__ Q, const u16* __restrict__ K,
    const u16* __restrict__ Vt, u16* __restrict__ ctx){
  __shared__ u16 buf[2][16384];  // per buffer: K [64][128] (8192 u16) then V [128][64]
  __shared__ u16 Psh[4*32*64];   // 16 KB: per-wave P [32 q][64 kv], XOR-swizzled
  int tid = threadIdx.x, w = tid >> 6, lane = tid & 63;
  int l15 = lane & 15, l4 = lane >> 4;
  int lin = blockIdx.x;
  int virt = (lin & 7) * 64 + (lin >> 3);
  int qt = virt & 15, bh = virt >> 4;
  int b = bh >> 4, h = bh & 15;
  const u16* Qg = Q + (size_t)(b*2048 + qt*128) * 2048 + h*128;
  const u16* Kg = K + (size_t)(b*2048) * 2048 + h*128;
  const u16* Vg = Vt + (size_t)bh * 128 * 2048;

  // prologue: Q -> buf[1], kv-tile 0 -> buf[0]
  #pragma unroll
  for (int i=0; i<8; ++i){
    int e = (i*256 + tid) * 8;
    int r = e >> 7, cc = e & 127;
    gload16(Qg + (size_t)r*2048 + cc, (char*)buf[1] + i*4096 + w*1024);
  }
  #pragma unroll
  for (int i=0; i<4; ++i){
    int e = (i*256 + tid) * 8;
    int r = e >> 7, cc = e & 127;
    gload16(Kg + (size_t)r*2048 + cc, (char*)buf[0] + i*4096 + w*1024);
    int dd = e >> 6, c2 = e & 63;
    gload16(Vg + (size_t)dd*2048 + c2, (char*)buf[0] + 16384 + i*4096 + w*1024);
  }
  __syncthreads();   // drains vmcnt

  bf16x8 qf[2][4];   // Q rows (pre-scaled by log2e/sqrt(dk)); used as B operand
  #pragma unroll
  for (int mi=0; mi<2; mi++){
    int r = w*32 + mi*16 + l15;
    #pragma unroll
    for (int kb=0; kb<4; kb++){
      int cc = (kb*32 + l4*8) ^ ((r & 7) << 3);
      qf[mi][kb] = *(const bf16x8*)(buf[1] + r*128 + cc);
    }
  }
  __syncthreads();   // all waves done with Q region before it becomes buffer 1

  f32x4 ctxa[2][8];
  #pragma unroll
  for (int mi=0; mi<2; mi++)
    #pragma unroll
    for (int nd=0; nd<8; nd++) ctxa[mi][nd] = (f32x4){0.f,0.f,0.f,0.f};
  float mrun[2] = {-3.0e38f, -3.0e38f};
  float lrun[2] = {0.f, 0.f};

  char* PwB = (char*)(Psh + w * (32*64));
  int psw = (l15 & 7) << 4;

  for (int t = 0; t < 32; ++t){
    int cur = t & 1;
    const u16* Kc = buf[cur];
    const u16* Vc = buf[cur] + 8192;
    if (t + 1 < 32){
      int kvn = (t + 1) * 64;
      char* bn = (char*)buf[cur ^ 1];
      #pragma unroll
      for (int i=0; i<4; ++i){
        int e = (i*256 + tid) * 8;
        int r = e >> 7, cc = e & 127;
        gload16(Kg + (size_t)(kvn + r)*2048 + cc, bn + i*4096 + w*1024);
        int dd = e >> 6, c2 = e & 63;
        gload16(Vg + (size_t)dd*2048 + kvn + c2, bn + 16384 + i*4096 + w*1024);
      }
    }
    // S^T = mfma(K, Q)
    f32x4 s[2][4];
    #pragma unroll
    for (int mi=0; mi<2; mi++)
      #pragma unroll
      for (int ni=0; ni<4; ni++) s[mi][ni] = (f32x4){0.f,0.f,0.f,0.f};
    __builtin_amdgcn_s_setprio(1);
    #pragma unroll
    for (int kb=0; kb<4; kb++){
      #pragma unroll
      for (int ni=0; ni<4; ni++){
        int r = ni*16 + l15;
        int cc = (kb*32 + l4*8) ^ ((r & 7) << 3);
        bf16x8 kf = *(const bf16x8*)(Kc + r*128 + cc);
        s[0][ni] = __builtin_amdgcn_mfma_f32_16x16x32_bf16(kf, qf[0][kb], s[0][ni], 0, 0, 0);
        s[1][ni] = __builtin_amdgcn_mfma_f32_16x16x32_bf16(kf, qf[1][kb], s[1][ni], 0, 0, 0);
      }
    }
    __builtin_amdgcn_s_setprio(0);
    float pm[2];
    #pragma unroll
    for (int mi=0; mi<2; mi++){
      float v = s[mi][0][0];
      #pragma unroll
      for (int ni=0; ni<4; ni++)
        #pragma unroll
        for (int j=0; j<4; j++) v = fmaxf(v, s[mi][ni][j]);
      v = fmaxf(v, __shfl_xor(v, 16));
      v = fmaxf(v, __shfl_xor(v, 32));
      pm[mi] = v;
    }
    bool need = (pm[0] > mrun[0] + RESCALE_THR) || (pm[1] > mrun[1] + RESCALE_THR);
    if (__any(need)){
      #pragma unroll
      for (int mi=0; mi<2; mi++){
        float mnew = fmaxf(mrun[mi], pm[mi]);
        float cr = exp2f(mrun[mi] - mnew);
        lrun[mi] *= cr;
        mrun[mi] = mnew;
        #pragma unroll
        for (int nd=0; nd<8; nd++) ctxa[mi][nd] *= cr;
      }
    }
    #pragma unroll
    for (int mi=0; mi<2; mi++){
      float ps = 0.f;
      #pragma unroll
      for (int ni=0; ni<4; ni++){
        float p0 = exp2f(s[mi][ni][0] - mrun[mi]);
        float p1 = exp2f(s[mi][ni][1] - mrun[mi]);
        float p2 = exp2f(s[mi][ni][2] - mrun[mi]);
        float p3 = exp2f(s[mi][ni][3] - mrun[mi]);
        ps += (p0 + p1) + (p2 + p3);
        uint2 pk = {cvt_pk_bf16(p0, p1), cvt_pk_bf16(p2, p3)};
        *(uint2*)(PwB + (mi*16 + l15)*128 + ((ni*32 + l4*8) ^ psw)) = pk;
      }
      ps += __shfl_xor(ps, 16);
      ps += __shfl_xor(ps, 32);
      lrun[mi] += ps;
    }
    bf16x8 pb[2][2];
    #pragma unroll
    for (int mi=0; mi<2; mi++)
      #pragma unroll
      for (int kvb=0; kvb<2; kvb++)
        pb[mi][kvb] = *(const bf16x8*)(PwB + (mi*16 + l15)*128 + ((kvb*64 + l4*16) ^ psw));
    __builtin_amdgcn_s_setprio(1);
    #pragma unroll
    for (int nd=0; nd<8; nd++){
      int dd = nd*16 + l15;
      int sw = (dd & 7) << 3;
      #pragma unroll
      for (int kvb=0; kvb<2; kvb++){
        bf16x8 vf = *(const bf16x8*)(Vc + dd*64 + ((kvb*32 + l4*8) ^ sw));
        ctxa[0][nd] = __builtin_amdgcn_mfma_f32_16x16x32_bf16(vf, pb[0][kvb], ctxa[0][nd], 0, 0, 0);
        ctxa[1][nd] = __builtin_amdgcn_mfma_f32_16x16x32_bf16(vf, pb[1][kvb], ctxa[1][nd], 0, 0, 0);
      }
    }
    __builtin_amdgcn_s_setprio(0);
    __syncthreads();
  }
  // epilogue: normalize, transpose through per-wave LDS region, coalesced store
  char* OwB = (char*)buf[0] + w*8192;
  #pragma unroll
  for (int mi=0; mi<2; mi++){
    float inv = 1.0f / lrun[mi];
    #pragma unroll
    for (int nd=0; nd<8; nd++){
      f32x4 c = ctxa[mi][nd] * inv;
      uint2 pk = {cvt_pk_bf16(c[0], c[1]), cvt_pk_bf16(c[2], c[3])};
      *(uint2*)(OwB + (mi*16 + l15)*256 + ((nd*32 + l4*8) ^ psw)) = pk;
    }
  }
  #pragma unroll
  for (int i=0; i<8; ++i){
    int row = i*4 + l4;
    int colb = l15*16;
    uint4 v = *(const uint4*)(OwB + row*256 + (colb ^ ((row & 7) << 4)));
    int srow = qt*128 + w*32 + row;
    *(uint4*)(ctx + ((size_t)(b*2048 + srow))*2048 + h*128 + colb/2) = v;
  }
}

// ---------------- launcher ----------------
extern "C" void kernel_launch(void* const* d_in, const int* in_sizes, int n_in,
                              void* d_out, int out_size, void* d_ws, size_t ws_size,
                              hipStream_t stream){
  const float* x  = (const float*)d_in[0];
  const float* Wq = (const float*)d_in[1];  const float* bq = (const float*)d_in[2];
  const float* Aq = (const float*)d_in[3];  const float* Bq = (const float*)d_in[4];
  const float* Wk = (const float*)d_in[5];  const float* bk = (const float*)d_in[6];
  const float* Ak = (const float*)d_in[7];  const float* Bk = (const float*)d_in[8];
  const float* Wv = (const float*)d_in[9];  const float* bv = (const float*)d_in[10];
  const float* Av = (const float*)d_in[11]; const float* Bv = (const float*)d_in[12];
  const float* Wo = (const float*)d_in[13]; const float* bo = (const float*)d_in[14];
  const float* Ao = (const float*)d_in[15]; const float* Bo = (const float*)d_in[16];

  char* ws = (char*)d_ws;
  size_t off = 0;
  u16* xbf  = (u16*)(ws + off); off += (size_t)4096*2048*2;          // 16 MB
  u16* wqkv = (u16*)(ws + off); off += (size_t)3*2048*2048*2;        // 24 MB
  u16* wob  = (u16*)(ws + off); off += (size_t)2048*2048*2;          // 8 MB
  float* xa = (float*)(ws + off); off += (size_t)4*32768*4;          // 4 slabs [4096][8]
  u16* Qb  = (u16*)(ws + off); off += (size_t)4096*2048*2;
  u16* Kb  = (u16*)(ws + off); off += (size_t)4096*2048*2;
  u16* Vb  = (u16*)(ws + off); off += (size_t)4096*2048*2;           // ctx buffer
  u16* Vtb = (u16*)(ws + off); off += (size_t)4096*2048*2;
  if (ws_size < off) return;

  cvt_w4<<<8192, 256, 0, stream>>>(Wq, Wk, Wv, Wo, wqkv, wob);
  lora_x_fused<<<1024, 256, 0, stream>>>(x, Aq, Ak, Av, xa, xbf);

  gemm_qkv<<<768, 256, 0, stream>>>(xbf, wqkv, bq, bk, bv, Bq, Bk, Bv, xa, Qb, Kb, Vtb);

  attn_kernel<<<512, 256, 0, stream>>>(Qb, Kb, Vtb, Vb);   // ctx -> Vb

  lora_xa_bf16<<<1024, 256, 0, stream>>>(Vb, Ao, xa+98304);

  gemm_o<<<256, 256, 0, stream>>>(Vb, wob, bo, Bo, xa+98304, (float*)d_out);
}

// Round 13
// 337.562 us; speedup vs baseline: 2.9684x; 2.9684x over previous
//
#include <hip/hip_runtime.h>
#include <stdint.h>

typedef unsigned short u16;
typedef unsigned int   u32;
typedef __bf16  bf16x8 __attribute__((ext_vector_type(8)));
typedef float   f32x4  __attribute__((ext_vector_type(4)));

#define LORA_SCALE 2.0f
#define QSCALE 0.08838834764831845f   // 1/sqrt(128)
#define LOG2E  1.4426950408889634f
#define RESCALE_THR 8.0f

__device__ __forceinline__ u16 f2bf(float f){
  u32 u = __builtin_bit_cast(u32, f);
  u32 r = (u + 0x7fffu + ((u >> 16) & 1u)) >> 16;   // RNE
  return (u16)r;
}
__device__ __forceinline__ float bf2f(u16 v){
  return __builtin_bit_cast(float, ((u32)v) << 16);
}
// pack 2 f32 -> 2 bf16 in one VALU op (no builtin on gfx950; T12 recipe)
__device__ __forceinline__ u32 cvt_pk_bf16(float lo, float hi){
  u32 d;
  asm("v_cvt_pk_bf16_f32 %0, %1, %2" : "=v"(d) : "v"(lo), "v"(hi));
  return d;
}

typedef __attribute__((address_space(3))) u32 lds_u32_t;
typedef __attribute__((address_space(1))) const u32 g_u32_t;

// async global->LDS, 16B per lane; LDS dest = wave-uniform base + lane*16
__device__ __forceinline__ void gload16(const void* g, void* l){
  __builtin_amdgcn_global_load_lds((g_u32_t*)(unsigned long long)g,
                                   (lds_u32_t*)(u32)(unsigned long long)l,
                                   16, 0, 0);
}

// ---------------- 4x W fp32 -> bf16 convert, one launch ----------------
__global__ __launch_bounds__(256) void cvt_w4(const float* __restrict__ W0,
    const float* __restrict__ W1, const float* __restrict__ W2,
    const float* __restrict__ W3, u16* __restrict__ wqkv, u16* __restrict__ wo){
  int sel = blockIdx.x >> 11;
  int inner = blockIdx.x & 2047;
  const float* src = sel==0 ? W0 : sel==1 ? W1 : sel==2 ? W2 : W3;
  u16* dst = sel<3 ? (wqkv + (size_t)sel*4194304) : wo;
  int i = (inner*256 + threadIdx.x) * 8;
  float4 a = *(const float4*)(src + i);
  float4 b = *(const float4*)(src + i + 4);
  u16 o[8] = {f2bf(a.x),f2bf(a.y),f2bf(a.z),f2bf(a.w),
              f2bf(b.x),f2bf(b.y),f2bf(b.z),f2bf(b.w)};
  *(uint4*)(dst + i) = *(const uint4*)o;
}

// ---------------- fused: x fp32 -> xbf bf16 AND xa[m][r] for 3 A's (1 row/wave) ----------------
__global__ __launch_bounds__(256) void lora_x_fused(const float* __restrict__ x,
    const float* __restrict__ A0, const float* __restrict__ A1, const float* __restrict__ A2,
    float* __restrict__ xout, u16* __restrict__ xbf){
  int w = threadIdx.x >> 6, lane = threadIdx.x & 63;
  int m = blockIdx.x * 4 + w;
  float acc[3][8];
  #pragma unroll
  for (int g=0; g<3; ++g)
    #pragma unroll
    for (int r=0; r<8; ++r) acc[g][r] = 0.f;
  const float* As[3] = {A0, A1, A2};
  #pragma unroll 1
  for (int it=0; it<8; ++it){
    int k = it*256 + lane*4;
    float4 xv = *(const float4*)(x + (size_t)m*2048 + k);
    u16 o[4] = {f2bf(xv.x), f2bf(xv.y), f2bf(xv.z), f2bf(xv.w)};
    *(uint2*)(xbf + (size_t)m*2048 + k) = *(const uint2*)o;
    #pragma unroll
    for (int g=0; g<3; ++g){
      const float* Ag = As[g];
      #pragma unroll
      for (int r=0; r<8; ++r){
        float4 av = *(const float4*)(Ag + r*2048 + k);
        acc[g][r] += xv.x*av.x + xv.y*av.y + xv.z*av.z + xv.w*av.w;
      }
    }
  }
  #pragma unroll
  for (int g=0; g<3; ++g)
    #pragma unroll
    for (int r=0; r<8; ++r){
      float v = acc[g][r];
      #pragma unroll
      for (int off=32; off; off>>=1) v += __shfl_xor(v, off);
      if (lane == 0) xout[g*32768 + m*8 + r] = v;
    }
}

// ---------------- LoRA stage 1 (ctx bf16 path, 1 row/wave) ----------------
__global__ __launch_bounds__(256) void lora_xa_bf16(const u16* __restrict__ xin,
    const float* __restrict__ A0, float* __restrict__ xout){
  int w = threadIdx.x >> 6, lane = threadIdx.x & 63;
  int m = blockIdx.x * 4 + w;
  float acc[8];
  #pragma unroll
  for (int r=0; r<8; ++r) acc[r] = 0.f;
  #pragma unroll 1
  for (int it=0; it<8; ++it){
    int k = it*256 + lane*4;
    ushort4 u = *(const ushort4*)(xin + (size_t)m*2048 + k);
    float4 xv = {bf2f(u.x), bf2f(u.y), bf2f(u.z), bf2f(u.w)};
    #pragma unroll
    for (int r=0; r<8; ++r){
      float4 av = *(const float4*)(A0 + r*2048 + k);
      acc[r] += xv.x*av.x + xv.y*av.y + xv.z*av.z + xv.w*av.w;
    }
  }
  #pragma unroll
  for (int r=0; r<8; ++r){
    float v = acc[r];
    #pragma unroll
    for (int off=32; off; off>>=1) v += __shfl_xor(v, off);
    if (lane == 0) xout[m*8 + r] = v;
  }
}

// ---------------- GEMM core v7: BM=256 BN=128 BK=32, 4 waves 2Mx2N, per-wave 128x64 ----------------
// Tri-buffered LDS (3 x 24KB); stage t+2 while computing t; vmcnt(6) once per K-step.
// NOTE (R12 lesson): per-wave 128x64 needs ~208 unified VGPR+AGPR -> 2 blocks/CU is a
// REGISTER ceiling; launch_bounds(256,3) spills acc to scratch (1.27GB writes, 5.9% MfmaUtil).
// T2 swizzle (verified 0-conflict): LDS 16B-slot s at row r holds global slot s^((r>>1)&3).
__device__ __forceinline__ void gemm_core_v7(
    const u16* __restrict__ Aptr,   // + m0*2048 (256 rows)
    const u16* __restrict__ Wptr,   // + n0g*2048 (128 rows)
    u16* lds, int tid, f32x4 acc[8][4]){
  const int Kd = 2048;
  int l = tid & 63, w = tid >> 6;
  int l15 = l & 15, l4 = l >> 4;
  int wm = w >> 1, wn = w & 1;
  char* L = (char*)lds;
  int wb = w * 1024;
  const u16* asrc[4]; const u16* bsrc[2];
  #pragma unroll
  for (int i=0;i<4;i++){ int row=(i*4+w)*16+(l>>2); int sc=((l&3)^((row>>1)&3))<<3;
    asrc[i] = Aptr + (size_t)row*Kd + sc; }
  #pragma unroll
  for (int i=0;i<2;i++){ int row=(i*4+w)*16+(l>>2); int sc=((l&3)^((row>>1)&3))<<3;
    bsrc[i] = Wptr + (size_t)row*Kd + sc; }
  int aoff[8], boff[4];
  #pragma unroll
  for (int mr=0;mr<8;mr++){ int ra=wm*128+mr*16+l15; aoff[mr]=ra*64+((l4^((ra>>1)&3))<<4); }
  #pragma unroll
  for (int nr=0;nr<4;nr++){ int rb=wn*64+nr*16+l15; boff[nr]=16384+rb*64+((l4^((rb>>1)&3))<<4); }

  auto STG = [&](int kt, int sbase){
    char* D = L + sbase;
    gload16(asrc[0]+kt, D +        wb);
    gload16(asrc[1]+kt, D +  4096+ wb);
    gload16(asrc[2]+kt, D +  8192+ wb);
    gload16(asrc[3]+kt, D + 12288+ wb);
    gload16(bsrc[0]+kt, D + 16384+ wb);
    gload16(bsrc[1]+kt, D + 20480+ wb);
  };

  STG(0, 0); STG(32, 24576);
  asm volatile("s_waitcnt vmcnt(6)" ::: "memory");   // K-step 0 resident
  __builtin_amdgcn_s_barrier();

  int bb = 0, sb = 49152, kt2 = 64;
  #pragma unroll 1
  for (int t = 0; t < 64; ++t){
    bf16x8 af[4], bf[4];
    #pragma unroll
    for (int mr=0;mr<4;mr++) af[mr] = *(const bf16x8*)(L + bb + aoff[mr]);
    #pragma unroll
    for (int nr=0;nr<4;nr++) bf[nr] = *(const bf16x8*)(L + bb + boff[nr]);
    if (t < 62) STG(kt2, sb);
    __builtin_amdgcn_s_barrier();
    __builtin_amdgcn_s_setprio(1);
    #pragma unroll
    for (int mr=0;mr<4;mr++)
      #pragma unroll
      for (int nr=0;nr<4;nr++)
        acc[mr][nr] = __builtin_amdgcn_mfma_f32_16x16x32_bf16(af[mr], bf[nr], acc[mr][nr], 0,0,0);
    __builtin_amdgcn_s_setprio(0);
    __builtin_amdgcn_s_barrier();
    bf16x8 ag[4];
    #pragma unroll
    for (int mr=0;mr<4;mr++) ag[mr] = *(const bf16x8*)(L + bb + aoff[mr+4]);
    if (t < 62)       asm volatile("s_waitcnt vmcnt(6)" ::: "memory");   // t+1 resident
    else if (t == 62) asm volatile("s_waitcnt vmcnt(0)" ::: "memory");
    __builtin_amdgcn_s_barrier();
    __builtin_amdgcn_s_setprio(1);
    #pragma unroll
    for (int mr=0;mr<4;mr++)
      #pragma unroll
      for (int nr=0;nr<4;nr++)
        acc[mr+4][nr] = __builtin_amdgcn_mfma_f32_16x16x32_bf16(ag[mr], bf[nr], acc[mr+4][nr], 0,0,0);
    __builtin_amdgcn_s_setprio(0);
    __builtin_amdgcn_s_barrier();
    bb = (bb == 49152) ? 0 : bb + 24576;
    sb = (sb == 49152) ? 0 : sb + 24576;
    kt2 += 32;
  }
}

// ---------------- fused QKV GEMM (256x128 tiles, 768 blocks, 4 waves) ----------------
// XCD map: XCD x owns mt {2x,2x+1} x all 48 nt -> A-slab L2-resident.
// V blocks write Vt directly (LDS transpose epilogue).
__global__ __launch_bounds__(256, 2) void gemm_qkv(
    const u16* __restrict__ A, const u16* __restrict__ W,
    const float* __restrict__ bq, const float* __restrict__ bk, const float* __restrict__ bv,
    const float* __restrict__ lBq, const float* __restrict__ lBk, const float* __restrict__ lBv,
    const float* __restrict__ xa, u16* __restrict__ Qb, u16* __restrict__ Kb, u16* __restrict__ Vtb){
  __shared__ u16 lds[36864];   // 72 KB: 3 bufs x 24 KB (V-epilogue reuses first 64 KB)
  int tid = threadIdx.x;
  int l = tid & 63, w = tid >> 6;
  int l15 = l & 15, l4 = l >> 4;
  int wm = w >> 1, wn = w & 1;
  int bid = blockIdx.x;
  int xcd = bid & 7, local = bid >> 3;           // local 0..95
  int mt = xcd*2 + (local >= 48);
  int nt = (local < 48) ? local : local - 48;
  int m0 = mt * 256, n0g = nt * 128;
  int which = nt >> 4;                            // 0=q 1=k 2=v
  int n0 = (nt & 15) * 128;
  const float* bias = which==0 ? bq : which==1 ? bk : bv;
  const float* lB   = which==0 ? lBq : which==1 ? lBk : lBv;
  const float* xs   = xa + which*32768;

  f32x4 acc[8][4];
  #pragma unroll
  for (int mr=0; mr<8; mr++)
    #pragma unroll
    for (int nr=0; nr<4; nr++) acc[mr][nr] = (f32x4){0.f,0.f,0.f,0.f};

  gemm_core_v7(A + (size_t)m0*2048, W + (size_t)n0g*2048, lds, tid, acc);

  float bvv[4]; float4 lb0[4], lb1[4];
  #pragma unroll
  for (int nr=0; nr<4; nr++){
    int col = n0 + wn*64 + nr*16 + l15;
    bvv[nr] = bias[col];
    lb0[nr] = *(const float4*)(lB + col*8);
    lb1[nr] = *(const float4*)(lB + col*8 + 4);
  }

  if (which == 2){
    // ---- V: transpose through LDS, write Vt[bh][d][s] with attn kv-swizzle ----
    __syncthreads();
    char* L = (char*)lds;
    #pragma unroll
    for (int mr=0; mr<8; mr++){
      float vv[4][4];   // [nr][j]
      #pragma unroll
      for (int j=0; j<4; j++){
        int r = m0 + wm*128 + mr*16 + l4*4 + j;
        float4 xv0 = *(const float4*)(xs + (size_t)r*8);
        float4 xv1 = *(const float4*)(xs + (size_t)r*8 + 4);
        #pragma unroll
        for (int nr=0; nr<4; nr++)
          vv[nr][j] = acc[mr][nr][j] + bvv[nr] + LORA_SCALE * (
              xv0.x*lb0[nr].x + xv0.y*lb0[nr].y + xv0.z*lb0[nr].z + xv0.w*lb0[nr].w +
              xv1.x*lb1[nr].x + xv1.y*lb1[nr].y + xv1.z*lb1[nr].z + xv1.w*lb1[nr].w);
      }
      int s_ = wm*128 + mr*16 + l4*4;
      #pragma unroll
      for (int nr=0; nr<4; nr++){
        int d = wn*64 + nr*16 + l15;
        uint2 pk = {cvt_pk_bf16(vv[nr][0], vv[nr][1]), cvt_pk_bf16(vv[nr][2], vv[nr][3])};
        *(uint2*)(L + d*512 + ((s_*2) ^ ((d & 31) << 4))) = pk;
      }
    }
    __syncthreads();
    int bq_ = m0 >> 11, s0 = m0 & 2047, h = n0 >> 7;
    u16* vt = Vtb + ((size_t)((bq_*16 + h)*128)) * 2048;
    #pragma unroll
    for (int i=0; i<16; ++i){
      int flat = i*4096 + tid*16;
      int d = flat >> 9, s2 = flat & 511;
      uint4 val = *(const uint4*)(L + d*512 + (s2 ^ ((d & 31) << 4)));
      int sa = s0 + (s2 >> 1);
      *(uint4*)(vt + (size_t)d*2048 + (sa & ~63) + ((sa & 63) ^ ((d & 7) << 3))) = val;
    }
    return;
  }

  // ---- Q/K: swizzled bf16 store ----
  u16* outp = (which == 0) ? Qb : Kb;
  float oscale = (which == 0) ? QSCALE*LOG2E : 1.0f;
  #pragma unroll
  for (int mr=0; mr<8; mr++)
    #pragma unroll
    for (int j=0; j<4; j++){
      int r = m0 + wm*128 + mr*16 + l4*4 + j;
      float4 xv0 = *(const float4*)(xs + (size_t)r*8);
      float4 xv1 = *(const float4*)(xs + (size_t)r*8 + 4);
      #pragma unroll
      for (int nr=0; nr<4; nr++){
        int col = n0 + wn*64 + nr*16 + l15;
        float v = acc[mr][nr][j] + bvv[nr] + LORA_SCALE * (
            xv0.x*lb0[nr].x + xv0.y*lb0[nr].y + xv0.z*lb0[nr].z + xv0.w*lb0[nr].w +
            xv1.x*lb1[nr].x + xv1.y*lb1[nr].y + xv1.z*lb1[nr].z + xv1.w*lb1[nr].w);
        v *= oscale;
        int cs = col ^ ((r & 7) << 3);
        outp[(size_t)r*2048 + cs] = f2bf(v);
      }
    }
}

// ---------------- O projection GEMM (256x128 tiles, 256 blocks, fp32 out) ----------------
__global__ __launch_bounds__(256, 2) void gemm_o(
    const u16* __restrict__ A, const u16* __restrict__ W,
    const float* __restrict__ bias, const float* __restrict__ lB,
    const float* __restrict__ xa, float* __restrict__ outp){
  __shared__ u16 lds[36864];   // 72 KB
  int tid = threadIdx.x;
  int l = tid & 63, w = tid >> 6;
  int l15 = l & 15, l4 = l >> 4;
  int wm = w >> 1, wn = w & 1;
  int bid = blockIdx.x;
  int xcd = bid & 7, local = bid >> 3;           // local 0..31
  int mt = xcd*2 + (local >= 16);
  int nt = local & 15;
  int m0 = mt * 256, n0 = nt * 128;

  f32x4 acc[8][4];
  #pragma unroll
  for (int mr=0; mr<8; mr++)
    #pragma unroll
    for (int nr=0; nr<4; nr++) acc[mr][nr] = (f32x4){0.f,0.f,0.f,0.f};

  gemm_core_v7(A + (size_t)m0*2048, W + (size_t)n0*2048, lds, tid, acc);

  float bv[4]; float4 lb0[4], lb1[4];
  #pragma unroll
  for (int nr=0; nr<4; nr++){
    int col = n0 + wn*64 + nr*16 + l15;
    bv[nr] = bias[col];
    lb0[nr] = *(const float4*)(lB + col*8);
    lb1[nr] = *(const float4*)(lB + col*8 + 4);
  }
  #pragma unroll
  for (int mr=0; mr<8; mr++)
    #pragma unroll
    for (int j=0; j<4; j++){
      int r = m0 + wm*128 + mr*16 + l4*4 + j;
      float4 xv0 = *(const float4*)(xa + (size_t)r*8);
      float4 xv1 = *(const float4*)(xa + (size_t)r*8 + 4);
      #pragma unroll
      for (int nr=0; nr<4; nr++){
        int col = n0 + wn*64 + nr*16 + l15;
        float v = acc[mr][nr][j] + bv[nr] + LORA_SCALE * (
            xv0.x*lb0[nr].x + xv0.y*lb0[nr].y + xv0.z*lb0[nr].z + xv0.w*lb0[nr].w +
            xv1.x*lb1[nr].x + xv1.y*lb1[nr].y + xv1.z*lb1[nr].z + xv1.w*lb1[nr].w);
        outp[(size_t)r*2048 + col] = v;
      }
    }
}

// ---------------- flash attention: QBLK=128, KVBLK=64, 4 waves x 32 q-rows ----------------
__global__ __launch_bounds__(256, 2) void attn_kernel(
    const u16* __restrict__ Q, const u16* __restrict__ K,
    const u16* __restrict__ Vt, u16* __restrict__ ctx){
  __shared__ u16 buf[2][16384];  // per buffer: K [64][128] (8192 u16) then V [128][64]
  __shared__ u16 Psh[4*32*64];   // 16 KB: per-wave P [32 q][64 kv], XOR-swizzled
  int tid = threadIdx.x, w = tid >> 6, lane = tid & 63;
  int l15 = lane & 15, l4 = lane >> 4;
  int lin = blockIdx.x;
  int virt = (lin & 7) * 64 + (lin >> 3);
  int qt = virt & 15, bh = virt >> 4;
  int b = bh >> 4, h = bh & 15;
  const u16* Qg = Q + (size_t)(b*2048 + qt*128) * 2048 + h*128;
  const u16* Kg = K + (size_t)(b*2048) * 2048 + h*128;
  const u16* Vg = Vt + (size_t)bh * 128 * 2048;

  // prologue: Q -> buf[1], kv-tile 0 -> buf[0]
  #pragma unroll
  for (int i=0; i<8; ++i){
    int e = (i*256 + tid) * 8;
    int r = e >> 7, cc = e & 127;
    gload16(Qg + (size_t)r*2048 + cc, (char*)buf[1] + i*4096 + w*1024);
  }
  #pragma unroll
  for (int i=0; i<4; ++i){
    int e = (i*256 + tid) * 8;
    int r = e >> 7, cc = e & 127;
    gload16(Kg + (size_t)r*2048 + cc, (char*)buf[0] + i*4096 + w*1024);
    int dd = e >> 6, c2 = e & 63;
    gload16(Vg + (size_t)dd*2048 + c2, (char*)buf[0] + 16384 + i*4096 + w*1024);
  }
  __syncthreads();   // drains vmcnt

  bf16x8 qf[2][4];   // Q rows (pre-scaled by log2e/sqrt(dk)); used as B operand
  #pragma unroll
  for (int mi=0; mi<2; mi++){
    int r = w*32 + mi*16 + l15;
    #pragma unroll
    for (int kb=0; kb<4; kb++){
      int cc = (kb*32 + l4*8) ^ ((r & 7) << 3);
      qf[mi][kb] = *(const bf16x8*)(buf[1] + r*128 + cc);
    }
  }
  __syncthreads();   // all waves done with Q region before it becomes buffer 1

  f32x4 ctxa[2][8];
  #pragma unroll
  for (int mi=0; mi<2; mi++)
    #pragma unroll
    for (int nd=0; nd<8; nd++) ctxa[mi][nd] = (f32x4){0.f,0.f,0.f,0.f};
  float mrun[2] = {-3.0e38f, -3.0e38f};
  float lrun[2] = {0.f, 0.f};

  char* PwB = (char*)(Psh + w * (32*64));
  int psw = (l15 & 7) << 4;

  for (int t = 0; t < 32; ++t){
    int cur = t & 1;
    const u16* Kc = buf[cur];
    const u16* Vc = buf[cur] + 8192;
    if (t + 1 < 32){
      int kvn = (t + 1) * 64;
      char* bn = (char*)buf[cur ^ 1];
      #pragma unroll
      for (int i=0; i<4; ++i){
        int e = (i*256 + tid) * 8;
        int r = e >> 7, cc = e & 127;
        gload16(Kg + (size_t)(kvn + r)*2048 + cc, bn + i*4096 + w*1024);
        int dd = e >> 6, c2 = e & 63;
        gload16(Vg + (size_t)dd*2048 + kvn + c2, bn + 16384 + i*4096 + w*1024);
      }
    }
    // S^T = mfma(K, Q)
    f32x4 s[2][4];
    #pragma unroll
    for (int mi=0; mi<2; mi++)
      #pragma unroll
      for (int ni=0; ni<4; ni++) s[mi][ni] = (f32x4){0.f,0.f,0.f,0.f};
    __builtin_amdgcn_s_setprio(1);
    #pragma unroll
    for (int kb=0; kb<4; kb++){
      #pragma unroll
      for (int ni=0; ni<4; ni++){
        int r = ni*16 + l15;
        int cc = (kb*32 + l4*8) ^ ((r & 7) << 3);
        bf16x8 kf = *(const bf16x8*)(Kc + r*128 + cc);
        s[0][ni] = __builtin_amdgcn_mfma_f32_16x16x32_bf16(kf, qf[0][kb], s[0][ni], 0, 0, 0);
        s[1][ni] = __builtin_amdgcn_mfma_f32_16x16x32_bf16(kf, qf[1][kb], s[1][ni], 0, 0, 0);
      }
    }
    __builtin_amdgcn_s_setprio(0);
    float pm[2];
    #pragma unroll
    for (int mi=0; mi<2; mi++){
      float v = s[mi][0][0];
      #pragma unroll
      for (int ni=0; ni<4; ni++)
        #pragma unroll
        for (int j=0; j<4; j++) v = fmaxf(v, s[mi][ni][j]);
      v = fmaxf(v, __shfl_xor(v, 16));
      v = fmaxf(v, __shfl_xor(v, 32));
      pm[mi] = v;
    }
    bool need = (pm[0] > mrun[0] + RESCALE_THR) || (pm[1] > mrun[1] + RESCALE_THR);
    if (__any(need)){
      #pragma unroll
      for (int mi=0; mi<2; mi++){
        float mnew = fmaxf(mrun[mi], pm[mi]);
        float cr = exp2f(mrun[mi] - mnew);
        lrun[mi] *= cr;
        mrun[mi] = mnew;
        #pragma unroll
        for (int nd=0; nd<8; nd++) ctxa[mi][nd] *= cr;
      }
    }
    #pragma unroll
    for (int mi=0; mi<2; mi++){
      float ps = 0.f;
      #pragma unroll
      for (int ni=0; ni<4; ni++){
        float p0 = exp2f(s[mi][ni][0] - mrun[mi]);
        float p1 = exp2f(s[mi][ni][1] - mrun[mi]);
        float p2 = exp2f(s[mi][ni][2] - mrun[mi]);
        float p3 = exp2f(s[mi][ni][3] - mrun[mi]);
        ps += (p0 + p1) + (p2 + p3);
        uint2 pk = {cvt_pk_bf16(p0, p1), cvt_pk_bf16(p2, p3)};
        *(uint2*)(PwB + (mi*16 + l15)*128 + ((ni*32 + l4*8) ^ psw)) = pk;
      }
      ps += __shfl_xor(ps, 16);
      ps += __shfl_xor(ps, 32);
      lrun[mi] += ps;
    }
    bf16x8 pb[2][2];
    #pragma unroll
    for (int mi=0; mi<2; mi++)
      #pragma unroll
      for (int kvb=0; kvb<2; kvb++)
        pb[mi][kvb] = *(const bf16x8*)(PwB + (mi*16 + l15)*128 + ((kvb*64 + l4*16) ^ psw));
    __builtin_amdgcn_s_setprio(1);
    #pragma unroll
    for (int nd=0; nd<8; nd++){
      int dd = nd*16 + l15;
      int sw = (dd & 7) << 3;
      #pragma unroll
      for (int kvb=0; kvb<2; kvb++){
        bf16x8 vf = *(const bf16x8*)(Vc + dd*64 + ((kvb*32 + l4*8) ^ sw));
        ctxa[0][nd] = __builtin_amdgcn_mfma_f32_16x16x32_bf16(vf, pb[0][kvb], ctxa[0][nd], 0, 0, 0);
        ctxa[1][nd] = __builtin_amdgcn_mfma_f32_16x16x32_bf16(vf, pb[1][kvb], ctxa[1][nd], 0, 0, 0);
      }
    }
    __builtin_amdgcn_s_setprio(0);
    __syncthreads();
  }
  // epilogue: normalize, transpose through per-wave LDS region, coalesced store
  char* OwB = (char*)buf[0] + w*8192;
  #pragma unroll
  for (int mi=0; mi<2; mi++){
    float inv = 1.0f / lrun[mi];
    #pragma unroll
    for (int nd=0; nd<8; nd++){
      f32x4 c = ctxa[mi][nd] * inv;
      uint2 pk = {cvt_pk_bf16(c[0], c[1]), cvt_pk_bf16(c[2], c[3])};
      *(uint2*)(OwB + (mi*16 + l15)*256 + ((nd*32 + l4*8) ^ psw)) = pk;
    }
  }
  #pragma unroll
  for (int i=0; i<8; ++i){
    int row = i*4 + l4;
    int colb = l15*16;
    uint4 v = *(const uint4*)(OwB + row*256 + (colb ^ ((row & 7) << 4)));
    int srow = qt*128 + w*32 + row;
    *(uint4*)(ctx + ((size_t)(b*2048 + srow))*2048 + h*128 + colb/2) = v;
  }
}

// ---------------- launcher ----------------
extern "C" void kernel_launch(void* const* d_in, const int* in_sizes, int n_in,
                              void* d_out, int out_size, void* d_ws, size_t ws_size,
                              hipStream_t stream){
  const float* x  = (const float*)d_in[0];
  const float* Wq = (const float*)d_in[1];  const float* bq = (const float*)d_in[2];
  const float* Aq = (const float*)d_in[3];  const float* Bq = (const float*)d_in[4];
  const float* Wk = (const float*)d_in[5];  const float* bk = (const float*)d_in[6];
  const float* Ak = (const float*)d_in[7];  const float* Bk = (const float*)d_in[8];
  const float* Wv = (const float*)d_in[9];  const float* bv = (const float*)d_in[10];
  const float* Av = (const float*)d_in[11]; const float* Bv = (const float*)d_in[12];
  const float* Wo = (const float*)d_in[13]; const float* bo = (const float*)d_in[14];
  const float* Ao = (const float*)d_in[15]; const float* Bo = (const float*)d_in[16];

  char* ws = (char*)d_ws;
  size_t off = 0;
  u16* xbf  = (u16*)(ws + off); off += (size_t)4096*2048*2;          // 16 MB
  u16* wqkv = (u16*)(ws + off); off += (size_t)3*2048*2048*2;        // 24 MB
  u16* wob  = (u16*)(ws + off); off += (size_t)2048*2048*2;          // 8 MB
  float* xa = (float*)(ws + off); off += (size_t)4*32768*4;          // 4 slabs [4096][8]
  u16* Qb  = (u16*)(ws + off); off += (size_t)4096*2048*2;
  u16* Kb  = (u16*)(ws + off); off += (size_t)4096*2048*2;
  u16* Vb  = (u16*)(ws + off); off += (size_t)4096*2048*2;           // ctx buffer
  u16* Vtb = (u16*)(ws + off); off += (size_t)4096*2048*2;
  if (ws_size < off) return;

  cvt_w4<<<8192, 256, 0, stream>>>(Wq, Wk, Wv, Wo, wqkv, wob);
  lora_x_fused<<<1024, 256, 0, stream>>>(x, Aq, Ak, Av, xa, xbf);

  gemm_qkv<<<768, 256, 0, stream>>>(xbf, wqkv, bq, bk, bv, Bq, Bk, Bv, xa, Qb, Kb, Vtb);

  attn_kernel<<<512, 256, 0, stream>>>(Qb, Kb, Vtb, Vb);   // ctx -> Vb

  lora_xa_bf16<<<1024, 256, 0, stream>>>(Vb, Ao, xa+98304);

  gemm_o<<<256, 256, 0, stream>>>(Vb, wob, bo, Bo, xa+98304, (float*)d_out);
}

// Round 14
// 333.200 us; speedup vs baseline: 3.0073x; 1.0131x over previous
//
#include <hip/hip_runtime.h>
#include <stdint.h>

typedef unsigned short u16;
typedef unsigned int   u32;
typedef __bf16  bf16x8 __attribute__((ext_vector_type(8)));
typedef float   f32x4  __attribute__((ext_vector_type(4)));

#define LORA_SCALE 2.0f
#define QSCALE 0.08838834764831845f   // 1/sqrt(128)
#define LOG2E  1.4426950408889634f
#define RESCALE_THR 8.0f

__device__ __forceinline__ u16 f2bf(float f){
  u32 u = __builtin_bit_cast(u32, f);
  u32 r = (u + 0x7fffu + ((u >> 16) & 1u)) >> 16;   // RNE
  return (u16)r;
}
__device__ __forceinline__ float bf2f(u16 v){
  return __builtin_bit_cast(float, ((u32)v) << 16);
}
// pack 2 f32 -> 2 bf16 in one VALU op (no builtin on gfx950; T12 recipe)
__device__ __forceinline__ u32 cvt_pk_bf16(float lo, float hi){
  u32 d;
  asm("v_cvt_pk_bf16_f32 %0, %1, %2" : "=v"(d) : "v"(lo), "v"(hi));
  return d;
}

typedef __attribute__((address_space(3))) u32 lds_u32_t;
typedef __attribute__((address_space(1))) const u32 g_u32_t;

// async global->LDS, 16B per lane; LDS dest = wave-uniform base + lane*16
__device__ __forceinline__ void gload16(const void* g, void* l){
  __builtin_amdgcn_global_load_lds((g_u32_t*)(unsigned long long)g,
                                   (lds_u32_t*)(u32)(unsigned long long)l,
                                   16, 0, 0);
}

// ---------------- merged: 4x W convert (blocks 0..8191) + x convert & xa for 3 A's (8192..9215) ----------------
__global__ __launch_bounds__(256) void cvt_lora(const float* __restrict__ W0,
    const float* __restrict__ W1, const float* __restrict__ W2, const float* __restrict__ W3,
    u16* __restrict__ wqkv, u16* __restrict__ wo,
    const float* __restrict__ x,
    const float* __restrict__ A0, const float* __restrict__ A1, const float* __restrict__ A2,
    float* __restrict__ xout, u16* __restrict__ xbf){
  int bid = blockIdx.x;
  if (bid < 8192){
    int sel = bid >> 11;
    int inner = bid & 2047;
    const float* src = sel==0 ? W0 : sel==1 ? W1 : sel==2 ? W2 : W3;
    u16* dst = sel<3 ? (wqkv + (size_t)sel*4194304) : wo;
    int i = (inner*256 + threadIdx.x) * 8;
    float4 a = *(const float4*)(src + i);
    float4 b = *(const float4*)(src + i + 4);
    u16 o[8] = {f2bf(a.x),f2bf(a.y),f2bf(a.z),f2bf(a.w),
                f2bf(b.x),f2bf(b.y),f2bf(b.z),f2bf(b.w)};
    *(uint4*)(dst + i) = *(const uint4*)o;
    return;
  }
  int w = threadIdx.x >> 6, lane = threadIdx.x & 63;
  int m = (bid - 8192) * 4 + w;
  float acc[3][8];
  #pragma unroll
  for (int g=0; g<3; ++g)
    #pragma unroll
    for (int r=0; r<8; ++r) acc[g][r] = 0.f;
  const float* As[3] = {A0, A1, A2};
  #pragma unroll 1
  for (int it=0; it<8; ++it){
    int k = it*256 + lane*4;
    float4 xv = *(const float4*)(x + (size_t)m*2048 + k);
    u16 o[4] = {f2bf(xv.x), f2bf(xv.y), f2bf(xv.z), f2bf(xv.w)};
    *(uint2*)(xbf + (size_t)m*2048 + k) = *(const uint2*)o;
    #pragma unroll
    for (int g=0; g<3; ++g){
      const float* Ag = As[g];
      #pragma unroll
      for (int r=0; r<8; ++r){
        float4 av = *(const float4*)(Ag + r*2048 + k);
        acc[g][r] += xv.x*av.x + xv.y*av.y + xv.z*av.z + xv.w*av.w;
      }
    }
  }
  #pragma unroll
  for (int g=0; g<3; ++g)
    #pragma unroll
    for (int r=0; r<8; ++r){
      float v = acc[g][r];
      #pragma unroll
      for (int off=32; off; off>>=1) v += __shfl_xor(v, off);
      if (lane == 0) xout[g*32768 + m*8 + r] = v;
    }
}

// ---------------- GEMM core v7: BM=256 BN=128 BK=32, 4 waves 2Mx2N, per-wave 128x64 ----------------
// Tri-buffered LDS (3 x 24KB); stage t+2 while computing t; vmcnt(6) once per K-step.
// NOTE (R12 lesson): per-wave 128x64 needs ~208 unified VGPR+AGPR -> 2 blocks/CU is a
// REGISTER ceiling; launch_bounds(256,3) spills acc to scratch (1.27GB writes, 5.9% MfmaUtil).
// T2 swizzle (verified 0-conflict): LDS 16B-slot s at row r holds global slot s^((r>>1)&3).
__device__ __forceinline__ void gemm_core_v7(
    const u16* __restrict__ Aptr,   // + m0*2048 (256 rows)
    const u16* __restrict__ Wptr,   // + n0g*2048 (128 rows)
    u16* lds, int tid, f32x4 acc[8][4]){
  const int Kd = 2048;
  int l = tid & 63, w = tid >> 6;
  int l15 = l & 15, l4 = l >> 4;
  int wm = w >> 1, wn = w & 1;
  char* L = (char*)lds;
  int wb = w * 1024;
  const u16* asrc[4]; const u16* bsrc[2];
  #pragma unroll
  for (int i=0;i<4;i++){ int row=(i*4+w)*16+(l>>2); int sc=((l&3)^((row>>1)&3))<<3;
    asrc[i] = Aptr + (size_t)row*Kd + sc; }
  #pragma unroll
  for (int i=0;i<2;i++){ int row=(i*4+w)*16+(l>>2); int sc=((l&3)^((row>>1)&3))<<3;
    bsrc[i] = Wptr + (size_t)row*Kd + sc; }
  int aoff[8], boff[4];
  #pragma unroll
  for (int mr=0;mr<8;mr++){ int ra=wm*128+mr*16+l15; aoff[mr]=ra*64+((l4^((ra>>1)&3))<<4); }
  #pragma unroll
  for (int nr=0;nr<4;nr++){ int rb=wn*64+nr*16+l15; boff[nr]=16384+rb*64+((l4^((rb>>1)&3))<<4); }

  auto STG = [&](int kt, int sbase){
    char* D = L + sbase;
    gload16(asrc[0]+kt, D +        wb);
    gload16(asrc[1]+kt, D +  4096+ wb);
    gload16(asrc[2]+kt, D +  8192+ wb);
    gload16(asrc[3]+kt, D + 12288+ wb);
    gload16(bsrc[0]+kt, D + 16384+ wb);
    gload16(bsrc[1]+kt, D + 20480+ wb);
  };

  STG(0, 0); STG(32, 24576);
  asm volatile("s_waitcnt vmcnt(6)" ::: "memory");   // K-step 0 resident
  __builtin_amdgcn_s_barrier();

  int bb = 0, sb = 49152, kt2 = 64;
  #pragma unroll 1
  for (int t = 0; t < 64; ++t){
    bf16x8 af[4], bf[4];
    #pragma unroll
    for (int mr=0;mr<4;mr++) af[mr] = *(const bf16x8*)(L + bb + aoff[mr]);
    #pragma unroll
    for (int nr=0;nr<4;nr++) bf[nr] = *(const bf16x8*)(L + bb + boff[nr]);
    if (t < 62) STG(kt2, sb);
    __builtin_amdgcn_s_barrier();
    __builtin_amdgcn_s_setprio(1);
    #pragma unroll
    for (int mr=0;mr<4;mr++)
      #pragma unroll
      for (int nr=0;nr<4;nr++)
        acc[mr][nr] = __builtin_amdgcn_mfma_f32_16x16x32_bf16(af[mr], bf[nr], acc[mr][nr], 0,0,0);
    __builtin_amdgcn_s_setprio(0);
    __builtin_amdgcn_s_barrier();
    bf16x8 ag[4];
    #pragma unroll
    for (int mr=0;mr<4;mr++) ag[mr] = *(const bf16x8*)(L + bb + aoff[mr+4]);
    if (t < 62)       asm volatile("s_waitcnt vmcnt(6)" ::: "memory");   // t+1 resident
    else if (t == 62) asm volatile("s_waitcnt vmcnt(0)" ::: "memory");
    __builtin_amdgcn_s_barrier();
    __builtin_amdgcn_s_setprio(1);
    #pragma unroll
    for (int mr=0;mr<4;mr++)
      #pragma unroll
      for (int nr=0;nr<4;nr++)
        acc[mr+4][nr] = __builtin_amdgcn_mfma_f32_16x16x32_bf16(ag[mr], bf[nr], acc[mr+4][nr], 0,0,0);
    __builtin_amdgcn_s_setprio(0);
    __builtin_amdgcn_s_barrier();
    bb = (bb == 49152) ? 0 : bb + 24576;
    sb = (sb == 49152) ? 0 : sb + 24576;
    kt2 += 32;
  }
}

// ---------------- fused QKV GEMM (256x128 tiles, 768 blocks, 4 waves) ----------------
// XCD map: XCD x owns mt {2x,2x+1} x all 48 nt -> A-slab L2-resident.
// V blocks write Vt directly (LDS transpose epilogue).
__global__ __launch_bounds__(256, 2) void gemm_qkv(
    const u16* __restrict__ A, const u16* __restrict__ W,
    const float* __restrict__ bq, const float* __restrict__ bk, const float* __restrict__ bv,
    const float* __restrict__ lBq, const float* __restrict__ lBk, const float* __restrict__ lBv,
    const float* __restrict__ xa, u16* __restrict__ Qb, u16* __restrict__ Kb, u16* __restrict__ Vtb){
  __shared__ u16 lds[36864];   // 72 KB: 3 bufs x 24 KB (V-epilogue reuses first 64 KB)
  int tid = threadIdx.x;
  int l = tid & 63, w = tid >> 6;
  int l15 = l & 15, l4 = l >> 4;
  int wm = w >> 1, wn = w & 1;
  int bid = blockIdx.x;
  int xcd = bid & 7, local = bid >> 3;           // local 0..95
  int mt = xcd*2 + (local >= 48);
  int nt = (local < 48) ? local : local - 48;
  int m0 = mt * 256, n0g = nt * 128;
  int which = nt >> 4;                            // 0=q 1=k 2=v
  int n0 = (nt & 15) * 128;
  const float* bias = which==0 ? bq : which==1 ? bk : bv;
  const float* lB   = which==0 ? lBq : which==1 ? lBk : lBv;
  const float* xs   = xa + which*32768;

  f32x4 acc[8][4];
  #pragma unroll
  for (int mr=0; mr<8; mr++)
    #pragma unroll
    for (int nr=0; nr<4; nr++) acc[mr][nr] = (f32x4){0.f,0.f,0.f,0.f};

  gemm_core_v7(A + (size_t)m0*2048, W + (size_t)n0g*2048, lds, tid, acc);

  float bvv[4]; float4 lb0[4], lb1[4];
  #pragma unroll
  for (int nr=0; nr<4; nr++){
    int col = n0 + wn*64 + nr*16 + l15;
    bvv[nr] = bias[col];
    lb0[nr] = *(const float4*)(lB + col*8);
    lb1[nr] = *(const float4*)(lB + col*8 + 4);
  }

  if (which == 2){
    // ---- V: transpose through LDS, write Vt[bh][d][s] with attn kv-swizzle ----
    __syncthreads();
    char* L = (char*)lds;
    #pragma unroll
    for (int mr=0; mr<8; mr++){
      float vv[4][4];   // [nr][j]
      #pragma unroll
      for (int j=0; j<4; j++){
        int r = m0 + wm*128 + mr*16 + l4*4 + j;
        float4 xv0 = *(const float4*)(xs + (size_t)r*8);
        float4 xv1 = *(const float4*)(xs + (size_t)r*8 + 4);
        #pragma unroll
        for (int nr=0; nr<4; nr++)
          vv[nr][j] = acc[mr][nr][j] + bvv[nr] + LORA_SCALE * (
              xv0.x*lb0[nr].x + xv0.y*lb0[nr].y + xv0.z*lb0[nr].z + xv0.w*lb0[nr].w +
              xv1.x*lb1[nr].x + xv1.y*lb1[nr].y + xv1.z*lb1[nr].z + xv1.w*lb1[nr].w);
      }
      int s_ = wm*128 + mr*16 + l4*4;
      #pragma unroll
      for (int nr=0; nr<4; nr++){
        int d = wn*64 + nr*16 + l15;
        uint2 pk = {cvt_pk_bf16(vv[nr][0], vv[nr][1]), cvt_pk_bf16(vv[nr][2], vv[nr][3])};
        *(uint2*)(L + d*512 + ((s_*2) ^ ((d & 31) << 4))) = pk;
      }
    }
    __syncthreads();
    int bq_ = m0 >> 11, s0 = m0 & 2047, h = n0 >> 7;
    u16* vt = Vtb + ((size_t)((bq_*16 + h)*128)) * 2048;
    #pragma unroll
    for (int i=0; i<16; ++i){
      int flat = i*4096 + tid*16;
      int d = flat >> 9, s2 = flat & 511;
      uint4 val = *(const uint4*)(L + d*512 + (s2 ^ ((d & 31) << 4)));
      int sa = s0 + (s2 >> 1);
      *(uint4*)(vt + (size_t)d*2048 + (sa & ~63) + ((sa & 63) ^ ((d & 7) << 3))) = val;
    }
    return;
  }

  // ---- Q/K: swizzled bf16 store ----
  u16* outp = (which == 0) ? Qb : Kb;
  float oscale = (which == 0) ? QSCALE*LOG2E : 1.0f;
  #pragma unroll
  for (int mr=0; mr<8; mr++)
    #pragma unroll
    for (int j=0; j<4; j++){
      int r = m0 + wm*128 + mr*16 + l4*4 + j;
      float4 xv0 = *(const float4*)(xs + (size_t)r*8);
      float4 xv1 = *(const float4*)(xs + (size_t)r*8 + 4);
      #pragma unroll
      for (int nr=0; nr<4; nr++){
        int col = n0 + wn*64 + nr*16 + l15;
        float v = acc[mr][nr][j] + bvv[nr] + LORA_SCALE * (
            xv0.x*lb0[nr].x + xv0.y*lb0[nr].y + xv0.z*lb0[nr].z + xv0.w*lb0[nr].w +
            xv1.x*lb1[nr].x + xv1.y*lb1[nr].y + xv1.z*lb1[nr].z + xv1.w*lb1[nr].w);
        v *= oscale;
        int cs = col ^ ((r & 7) << 3);
        outp[(size_t)r*2048 + cs] = f2bf(v);
      }
    }
}

// ---------------- O projection GEMM (256x128 tiles, 256 blocks, fp32 out) ----------------
__global__ __launch_bounds__(256, 2) void gemm_o(
    const u16* __restrict__ A, const u16* __restrict__ W,
    const float* __restrict__ bias, const float* __restrict__ lB,
    const float* __restrict__ xa, float* __restrict__ outp){
  __shared__ u16 lds[36864];   // 72 KB
  int tid = threadIdx.x;
  int l = tid & 63, w = tid >> 6;
  int l15 = l & 15, l4 = l >> 4;
  int wm = w >> 1, wn = w & 1;
  int bid = blockIdx.x;
  int xcd = bid & 7, local = bid >> 3;           // local 0..31
  int mt = xcd*2 + (local >= 16);
  int nt = local & 15;
  int m0 = mt * 256, n0 = nt * 128;

  f32x4 acc[8][4];
  #pragma unroll
  for (int mr=0; mr<8; mr++)
    #pragma unroll
    for (int nr=0; nr<4; nr++) acc[mr][nr] = (f32x4){0.f,0.f,0.f,0.f};

  gemm_core_v7(A + (size_t)m0*2048, W + (size_t)n0*2048, lds, tid, acc);

  float bv[4]; float4 lb0[4], lb1[4];
  #pragma unroll
  for (int nr=0; nr<4; nr++){
    int col = n0 + wn*64 + nr*16 + l15;
    bv[nr] = bias[col];
    lb0[nr] = *(const float4*)(lB + col*8);
    lb1[nr] = *(const float4*)(lB + col*8 + 4);
  }
  #pragma unroll
  for (int mr=0; mr<8; mr++)
    #pragma unroll
    for (int j=0; j<4; j++){
      int r = m0 + wm*128 + mr*16 + l4*4 + j;
      float4 xv0 = *(const float4*)(xa + (size_t)r*8);
      float4 xv1 = *(const float4*)(xa + (size_t)r*8 + 4);
      #pragma unroll
      for (int nr=0; nr<4; nr++){
        int col = n0 + wn*64 + nr*16 + l15;
        float v = acc[mr][nr][j] + bv[nr] + LORA_SCALE * (
            xv0.x*lb0[nr].x + xv0.y*lb0[nr].y + xv0.z*lb0[nr].z + xv0.w*lb0[nr].w +
            xv1.x*lb1[nr].x + xv1.y*lb1[nr].y + xv1.z*lb1[nr].z + xv1.w*lb1[nr].w);
        outp[(size_t)r*2048 + col] = v;
      }
    }
}

// ---------------- flash attention: QBLK=128, KVBLK=64, 4 waves x 32 q-rows ----------------
// Epilogue additionally accumulates xa_o = ctx @ Ao^T partials (this head's 128 cols)
// via fp32 global atomicAdd -> replaces the standalone lora_xa kernel.
__global__ __launch_bounds__(256, 2) void attn_kernel(
    const u16* __restrict__ Q, const u16* __restrict__ K,
    const u16* __restrict__ Vt, u16* __restrict__ ctx,
    const float* __restrict__ Ao, float* __restrict__ xao){
  __shared__ u16 buf[2][16384];  // per buffer: K [64][128] (8192 u16) then V [128][64]
  __shared__ u16 Psh[4*32*64];   // 16 KB: per-wave P [32 q][64 kv], XOR-swizzled
  int tid = threadIdx.x, w = tid >> 6, lane = tid & 63;
  int l15 = lane & 15, l4 = lane >> 4;
  int lin = blockIdx.x;
  int virt = (lin & 7) * 64 + (lin >> 3);
  int qt = virt & 15, bh = virt >> 4;
  int b = bh >> 4, h = bh & 15;
  const u16* Qg = Q + (size_t)(b*2048 + qt*128) * 2048 + h*128;
  const u16* Kg = K + (size_t)(b*2048) * 2048 + h*128;
  const u16* Vg = Vt + (size_t)bh * 128 * 2048;

  // prologue: Q -> buf[1], kv-tile 0 -> buf[0]
  #pragma unroll
  for (int i=0; i<8; ++i){
    int e = (i*256 + tid) * 8;
    int r = e >> 7, cc = e & 127;
    gload16(Qg + (size_t)r*2048 + cc, (char*)buf[1] + i*4096 + w*1024);
  }
  #pragma unroll
  for (int i=0; i<4; ++i){
    int e = (i*256 + tid) * 8;
    int r = e >> 7, cc = e & 127;
    gload16(Kg + (size_t)r*2048 + cc, (char*)buf[0] + i*4096 + w*1024);
    int dd = e >> 6, c2 = e & 63;
    gload16(Vg + (size_t)dd*2048 + c2, (char*)buf[0] + 16384 + i*4096 + w*1024);
  }
  __syncthreads();   // drains vmcnt

  bf16x8 qf[2][4];   // Q rows (pre-scaled by log2e/sqrt(dk)); used as B operand
  #pragma unroll
  for (int mi=0; mi<2; mi++){
    int r = w*32 + mi*16 + l15;
    #pragma unroll
    for (int kb=0; kb<4; kb++){
      int cc = (kb*32 + l4*8) ^ ((r & 7) << 3);
      qf[mi][kb] = *(const bf16x8*)(buf[1] + r*128 + cc);
    }
  }
  __syncthreads();   // all waves done with Q region before it becomes buffer 1

  f32x4 ctxa[2][8];
  #pragma unroll
  for (int mi=0; mi<2; mi++)
    #pragma unroll
    for (int nd=0; nd<8; nd++) ctxa[mi][nd] = (f32x4){0.f,0.f,0.f,0.f};
  float mrun[2] = {-3.0e38f, -3.0e38f};
  float lrun[2] = {0.f, 0.f};

  char* PwB = (char*)(Psh + w * (32*64));
  int psw = (l15 & 7) << 4;

  for (int t = 0; t < 32; ++t){
    int cur = t & 1;
    const u16* Kc = buf[cur];
    const u16* Vc = buf[cur] + 8192;
    if (t + 1 < 32){
      int kvn = (t + 1) * 64;
      char* bn = (char*)buf[cur ^ 1];
      #pragma unroll
      for (int i=0; i<4; ++i){
        int e = (i*256 + tid) * 8;
        int r = e >> 7, cc = e & 127;
        gload16(Kg + (size_t)(kvn + r)*2048 + cc, bn + i*4096 + w*1024);
        int dd = e >> 6, c2 = e & 63;
        gload16(Vg + (size_t)dd*2048 + kvn + c2, bn + 16384 + i*4096 + w*1024);
      }
    }
    // S^T = mfma(K, Q)
    f32x4 s[2][4];
    #pragma unroll
    for (int mi=0; mi<2; mi++)
      #pragma unroll
      for (int ni=0; ni<4; ni++) s[mi][ni] = (f32x4){0.f,0.f,0.f,0.f};
    __builtin_amdgcn_s_setprio(1);
    #pragma unroll
    for (int kb=0; kb<4; kb++){
      #pragma unroll
      for (int ni=0; ni<4; ni++){
        int r = ni*16 + l15;
        int cc = (kb*32 + l4*8) ^ ((r & 7) << 3);
        bf16x8 kf = *(const bf16x8*)(Kc + r*128 + cc);
        s[0][ni] = __builtin_amdgcn_mfma_f32_16x16x32_bf16(kf, qf[0][kb], s[0][ni], 0, 0, 0);
        s[1][ni] = __builtin_amdgcn_mfma_f32_16x16x32_bf16(kf, qf[1][kb], s[1][ni], 0, 0, 0);
      }
    }
    __builtin_amdgcn_s_setprio(0);
    float pm[2];
    #pragma unroll
    for (int mi=0; mi<2; mi++){
      float v = s[mi][0][0];
      #pragma unroll
      for (int ni=0; ni<4; ni++)
        #pragma unroll
        for (int j=0; j<4; j++) v = fmaxf(v, s[mi][ni][j]);
      v = fmaxf(v, __shfl_xor(v, 16));
      v = fmaxf(v, __shfl_xor(v, 32));
      pm[mi] = v;
    }
    bool need = (pm[0] > mrun[0] + RESCALE_THR) || (pm[1] > mrun[1] + RESCALE_THR);
    if (__any(need)){
      #pragma unroll
      for (int mi=0; mi<2; mi++){
        float mnew = fmaxf(mrun[mi], pm[mi]);
        float cr = exp2f(mrun[mi] - mnew);
        lrun[mi] *= cr;
        mrun[mi] = mnew;
        #pragma unroll
        for (int nd=0; nd<8; nd++) ctxa[mi][nd] *= cr;
      }
    }
    #pragma unroll
    for (int mi=0; mi<2; mi++){
      float ps = 0.f;
      #pragma unroll
      for (int ni=0; ni<4; ni++){
        float p0 = exp2f(s[mi][ni][0] - mrun[mi]);
        float p1 = exp2f(s[mi][ni][1] - mrun[mi]);
        float p2 = exp2f(s[mi][ni][2] - mrun[mi]);
        float p3 = exp2f(s[mi][ni][3] - mrun[mi]);
        ps += (p0 + p1) + (p2 + p3);
        uint2 pk = {cvt_pk_bf16(p0, p1), cvt_pk_bf16(p2, p3)};
        *(uint2*)(PwB + (mi*16 + l15)*128 + ((ni*32 + l4*8) ^ psw)) = pk;
      }
      ps += __shfl_xor(ps, 16);
      ps += __shfl_xor(ps, 32);
      lrun[mi] += ps;
    }
    bf16x8 pb[2][2];
    #pragma unroll
    for (int mi=0; mi<2; mi++)
      #pragma unroll
      for (int kvb=0; kvb<2; kvb++)
        pb[mi][kvb] = *(const bf16x8*)(PwB + (mi*16 + l15)*128 + ((kvb*64 + l4*16) ^ psw));
    __builtin_amdgcn_s_setprio(1);
    #pragma unroll
    for (int nd=0; nd<8; nd++){
      int dd = nd*16 + l15;
      int sw = (dd & 7) << 3;
      #pragma unroll
      for (int kvb=0; kvb<2; kvb++){
        bf16x8 vf = *(const bf16x8*)(Vc + dd*64 + ((kvb*32 + l4*8) ^ sw));
        ctxa[0][nd] = __builtin_amdgcn_mfma_f32_16x16x32_bf16(vf, pb[0][kvb], ctxa[0][nd], 0, 0, 0);
        ctxa[1][nd] = __builtin_amdgcn_mfma_f32_16x16x32_bf16(vf, pb[1][kvb], ctxa[1][nd], 0, 0, 0);
      }
    }
    __builtin_amdgcn_s_setprio(0);
    __syncthreads();
  }
  // epilogue: normalize; write ctx (LDS transpose, coalesced); accumulate xa_o partials.
  char* OwB = (char*)buf[0] + w*8192;
  const float* AoH = Ao + h*128;   // Ao[8][2048], this head's 128-col slice
  #pragma unroll
  for (int mi=0; mi<2; mi++){
    float inv = 1.0f / lrun[mi];
    f32x4 cn[8];
    #pragma unroll
    for (int nd=0; nd<8; nd++){
      cn[nd] = ctxa[mi][nd] * inv;
      uint2 pk = {cvt_pk_bf16(cn[nd][0], cn[nd][1]), cvt_pk_bf16(cn[nd][2], cn[nd][3])};
      *(uint2*)(OwB + (mi*16 + l15)*256 + ((nd*32 + l4*8) ^ psw)) = pk;
    }
    // xa_o partial: this lane covers q = mi*16+l15 (32 d-values: nd*16 + l4*4 + j)
    int mglob = b*2048 + qt*128 + w*32 + mi*16 + l15;
    #pragma unroll
    for (int r=0; r<8; r++){
      float a = 0.f;
      #pragma unroll
      for (int nd=0; nd<8; nd++){
        float4 av = *(const float4*)(AoH + r*2048 + nd*16 + l4*4);
        a += cn[nd][0]*av.x + cn[nd][1]*av.y + cn[nd][2]*av.z + cn[nd][3]*av.w;
      }
      a += __shfl_xor(a, 16);
      a += __shfl_xor(a, 32);
      if (lane < 16) atomicAdd(xao + mglob*8 + r, a);
    }
  }
  #pragma unroll
  for (int i=0; i<8; ++i){
    int row = i*4 + l4;
    int colb = l15*16;
    uint4 v = *(const uint4*)(OwB + row*256 + (colb ^ ((row & 7) << 4)));
    int srow = qt*128 + w*32 + row;
    *(uint4*)(ctx + ((size_t)(b*2048 + srow))*2048 + h*128 + colb/2) = v;
  }
}

// ---------------- launcher ----------------
extern "C" void kernel_launch(void* const* d_in, const int* in_sizes, int n_in,
                              void* d_out, int out_size, void* d_ws, size_t ws_size,
                              hipStream_t stream){
  const float* x  = (const float*)d_in[0];
  const float* Wq = (const float*)d_in[1];  const float* bq = (const float*)d_in[2];
  const float* Aq = (const float*)d_in[3];  const float* Bq = (const float*)d_in[4];
  const float* Wk = (const float*)d_in[5];  const float* bk = (const float*)d_in[6];
  const float* Ak = (const float*)d_in[7];  const float* Bk = (const float*)d_in[8];
  const float* Wv = (const float*)d_in[9];  const float* bv = (const float*)d_in[10];
  const float* Av = (const float*)d_in[11]; const float* Bv = (const float*)d_in[12];
  const float* Wo = (const float*)d_in[13]; const float* bo = (const float*)d_in[14];
  const float* Ao = (const float*)d_in[15]; const float* Bo = (const float*)d_in[16];

  char* ws = (char*)d_ws;
  size_t off = 0;
  u16* xbf  = (u16*)(ws + off); off += (size_t)4096*2048*2;          // 16 MB
  u16* wqkv = (u16*)(ws + off); off += (size_t)3*2048*2048*2;        // 24 MB
  u16* wob  = (u16*)(ws + off); off += (size_t)2048*2048*2;          // 8 MB
  float* xa = (float*)(ws + off); off += (size_t)4*32768*4;          // 4 slabs [4096][8]
  u16* Qb  = (u16*)(ws + off); off += (size_t)4096*2048*2;
  u16* Kb  = (u16*)(ws + off); off += (size_t)4096*2048*2;
  u16* Vb  = (u16*)(ws + off); off += (size_t)4096*2048*2;           // ctx buffer
  u16* Vtb = (u16*)(ws + off); off += (size_t)4096*2048*2;
  if (ws_size < off) return;
  float* xao = xa + 98304;

  cvt_lora<<<9216, 256, 0, stream>>>(Wq, Wk, Wv, Wo, wqkv, wob, x, Aq, Ak, Av, xa, xbf);

  gemm_qkv<<<768, 256, 0, stream>>>(xbf, wqkv, bq, bk, bv, Bq, Bk, Bv, xa, Qb, Kb, Vtb);

  hipMemsetAsync(xao, 0, 32768*4, stream);   // zero xa_o accumulator (graph-capture safe)

  attn_kernel<<<512, 256, 0, stream>>>(Qb, Kb, Vtb, Vb, Ao, xao);   // ctx -> Vb, xa_o via atomics

  gemm_o<<<256, 256, 0, stream>>>(Vb, wob, bo, Bo, xao, (float*)d_out);
}

// Round 15
// 332.421 us; speedup vs baseline: 3.0143x; 1.0023x over previous
//
#include <hip/hip_runtime.h>
#include <stdint.h>

typedef unsigned short u16;
typedef unsigned int   u32;
typedef __bf16  bf16x8 __attribute__((ext_vector_type(8)));
typedef float   f32x4  __attribute__((ext_vector_type(4)));

#define LORA_SCALE 2.0f
#define QSCALE 0.08838834764831845f   // 1/sqrt(128)
#define LOG2E  1.4426950408889634f
#define RESCALE_THR 8.0f

__device__ __forceinline__ u16 f2bf(float f){
  u32 u = __builtin_bit_cast(u32, f);
  u32 r = (u + 0x7fffu + ((u >> 16) & 1u)) >> 16;   // RNE
  return (u16)r;
}
__device__ __forceinline__ float bf2f(u16 v){
  return __builtin_bit_cast(float, ((u32)v) << 16);
}
// pack 2 f32 -> 2 bf16 in one VALU op (no builtin on gfx950; T12 recipe)
__device__ __forceinline__ u32 cvt_pk_bf16(float lo, float hi){
  u32 d;
  asm("v_cvt_pk_bf16_f32 %0, %1, %2" : "=v"(d) : "v"(lo), "v"(hi));
  return d;
}

typedef __attribute__((address_space(3))) u32 lds_u32_t;
typedef __attribute__((address_space(1))) const u32 g_u32_t;

// async global->LDS, 16B per lane; LDS dest = wave-uniform base + lane*16
__device__ __forceinline__ void gload16(const void* g, void* l){
  __builtin_amdgcn_global_load_lds((g_u32_t*)(unsigned long long)g,
                                   (lds_u32_t*)(u32)(unsigned long long)l,
                                   16, 0, 0);
}

// ---------------- merged: 4x W convert (0..8191) + x convert & xa (8192..9215) + xao zero (9216) ----------------
__global__ __launch_bounds__(256) void cvt_lora(const float* __restrict__ W0,
    const float* __restrict__ W1, const float* __restrict__ W2, const float* __restrict__ W3,
    u16* __restrict__ wqkv, u16* __restrict__ wo,
    const float* __restrict__ x,
    const float* __restrict__ A0, const float* __restrict__ A1, const float* __restrict__ A2,
    float* __restrict__ xout, u16* __restrict__ xbf, float* __restrict__ xao){
  int bid = blockIdx.x;
  if (bid < 8192){
    int sel = bid >> 11;
    int inner = bid & 2047;
    const float* src = sel==0 ? W0 : sel==1 ? W1 : sel==2 ? W2 : W3;
    u16* dst = sel<3 ? (wqkv + (size_t)sel*4194304) : wo;
    int i = (inner*256 + threadIdx.x) * 8;
    float4 a = *(const float4*)(src + i);
    float4 b = *(const float4*)(src + i + 4);
    u16 o[8] = {f2bf(a.x),f2bf(a.y),f2bf(a.z),f2bf(a.w),
                f2bf(b.x),f2bf(b.y),f2bf(b.z),f2bf(b.w)};
    *(uint4*)(dst + i) = *(const uint4*)o;
    return;
  }
  if (bid == 9216){
    // zero the xa_o atomic accumulator (32768 floats)
    float4 z = {0.f,0.f,0.f,0.f};
    #pragma unroll
    for (int i=0; i<32; ++i)
      *(float4*)(xao + (i*256 + threadIdx.x)*4) = z;
    return;
  }
  int w = threadIdx.x >> 6, lane = threadIdx.x & 63;
  int m = (bid - 8192) * 4 + w;
  float acc[3][8];
  #pragma unroll
  for (int g=0; g<3; ++g)
    #pragma unroll
    for (int r=0; r<8; ++r) acc[g][r] = 0.f;
  const float* As[3] = {A0, A1, A2};
  #pragma unroll 1
  for (int it=0; it<8; ++it){
    int k = it*256 + lane*4;
    float4 xv = *(const float4*)(x + (size_t)m*2048 + k);
    u16 o[4] = {f2bf(xv.x), f2bf(xv.y), f2bf(xv.z), f2bf(xv.w)};
    *(uint2*)(xbf + (size_t)m*2048 + k) = *(const uint2*)o;
    #pragma unroll
    for (int g=0; g<3; ++g){
      const float* Ag = As[g];
      #pragma unroll
      for (int r=0; r<8; ++r){
        float4 av = *(const float4*)(Ag + r*2048 + k);
        acc[g][r] += xv.x*av.x + xv.y*av.y + xv.z*av.z + xv.w*av.w;
      }
    }
  }
  #pragma unroll
  for (int g=0; g<3; ++g)
    #pragma unroll
    for (int r=0; r<8; ++r){
      float v = acc[g][r];
      #pragma unroll
      for (int off=32; off; off>>=1) v += __shfl_xor(v, off);
      if (lane == 0) xout[g*32768 + m*8 + r] = v;
    }
}

// ---------------- GEMM core v7: BM=256 BN=128 BK=32, 4 waves 2Mx2N, per-wave 128x64 ----------------
// Tri-buffered LDS (3 x 24KB); stage t+2 while computing t; vmcnt(6) once per K-step.
// NOTE (R12 lesson): per-wave 128x64 needs ~208 unified VGPR+AGPR -> 2 blocks/CU is a
// REGISTER ceiling; launch_bounds(256,3) spills acc to scratch (1.27GB writes, 5.9% MfmaUtil).
// T2 swizzle (verified 0-conflict): LDS 16B-slot s at row r holds global slot s^((r>>1)&3).
__device__ __forceinline__ void gemm_core_v7(
    const u16* __restrict__ Aptr,   // + m0*2048 (256 rows)
    const u16* __restrict__ Wptr,   // + n0g*2048 (128 rows)
    u16* lds, int tid, f32x4 acc[8][4]){
  const int Kd = 2048;
  int l = tid & 63, w = tid >> 6;
  int l15 = l & 15, l4 = l >> 4;
  int wm = w >> 1, wn = w & 1;
  char* L = (char*)lds;
  int wb = w * 1024;
  const u16* asrc[4]; const u16* bsrc[2];
  #pragma unroll
  for (int i=0;i<4;i++){ int row=(i*4+w)*16+(l>>2); int sc=((l&3)^((row>>1)&3))<<3;
    asrc[i] = Aptr + (size_t)row*Kd + sc; }
  #pragma unroll
  for (int i=0;i<2;i++){ int row=(i*4+w)*16+(l>>2); int sc=((l&3)^((row>>1)&3))<<3;
    bsrc[i] = Wptr + (size_t)row*Kd + sc; }
  int aoff[8], boff[4];
  #pragma unroll
  for (int mr=0;mr<8;mr++){ int ra=wm*128+mr*16+l15; aoff[mr]=ra*64+((l4^((ra>>1)&3))<<4); }
  #pragma unroll
  for (int nr=0;nr<4;nr++){ int rb=wn*64+nr*16+l15; boff[nr]=16384+rb*64+((l4^((rb>>1)&3))<<4); }

  auto STG = [&](int kt, int sbase){
    char* D = L + sbase;
    gload16(asrc[0]+kt, D +        wb);
    gload16(asrc[1]+kt, D +  4096+ wb);
    gload16(asrc[2]+kt, D +  8192+ wb);
    gload16(asrc[3]+kt, D + 12288+ wb);
    gload16(bsrc[0]+kt, D + 16384+ wb);
    gload16(bsrc[1]+kt, D + 20480+ wb);
  };

  STG(0, 0); STG(32, 24576);
  asm volatile("s_waitcnt vmcnt(6)" ::: "memory");   // K-step 0 resident
  __builtin_amdgcn_s_barrier();

  int bb = 0, sb = 49152, kt2 = 64;
  #pragma unroll 1
  for (int t = 0; t < 64; ++t){
    bf16x8 af[4], bf[4];
    #pragma unroll
    for (int mr=0;mr<4;mr++) af[mr] = *(const bf16x8*)(L + bb + aoff[mr]);
    #pragma unroll
    for (int nr=0;nr<4;nr++) bf[nr] = *(const bf16x8*)(L + bb + boff[nr]);
    if (t < 62) STG(kt2, sb);
    __builtin_amdgcn_s_barrier();
    __builtin_amdgcn_s_setprio(1);
    #pragma unroll
    for (int mr=0;mr<4;mr++)
      #pragma unroll
      for (int nr=0;nr<4;nr++)
        acc[mr][nr] = __builtin_amdgcn_mfma_f32_16x16x32_bf16(af[mr], bf[nr], acc[mr][nr], 0,0,0);
    __builtin_amdgcn_s_setprio(0);
    __builtin_amdgcn_s_barrier();
    bf16x8 ag[4];
    #pragma unroll
    for (int mr=0;mr<4;mr++) ag[mr] = *(const bf16x8*)(L + bb + aoff[mr+4]);
    if (t < 62)       asm volatile("s_waitcnt vmcnt(6)" ::: "memory");   // t+1 resident
    else if (t == 62) asm volatile("s_waitcnt vmcnt(0)" ::: "memory");
    __builtin_amdgcn_s_barrier();
    __builtin_amdgcn_s_setprio(1);
    #pragma unroll
    for (int mr=0;mr<4;mr++)
      #pragma unroll
      for (int nr=0;nr<4;nr++)
        acc[mr+4][nr] = __builtin_amdgcn_mfma_f32_16x16x32_bf16(ag[mr], bf[nr], acc[mr+4][nr], 0,0,0);
    __builtin_amdgcn_s_setprio(0);
    __builtin_amdgcn_s_barrier();
    bb = (bb == 49152) ? 0 : bb + 24576;
    sb = (sb == 49152) ? 0 : sb + 24576;
    kt2 += 32;
  }
}

// ---------------- fused QKV GEMM (256x128 tiles, 768 blocks, 4 waves) ----------------
// XCD map: XCD x owns mt {2x,2x+1} x all 48 nt -> A-slab L2-resident.
// V blocks write Vt directly (LDS transpose epilogue).
__global__ __launch_bounds__(256, 2) void gemm_qkv(
    const u16* __restrict__ A, const u16* __restrict__ W,
    const float* __restrict__ bq, const float* __restrict__ bk, const float* __restrict__ bv,
    const float* __restrict__ lBq, const float* __restrict__ lBk, const float* __restrict__ lBv,
    const float* __restrict__ xa, u16* __restrict__ Qb, u16* __restrict__ Kb, u16* __restrict__ Vtb){
  __shared__ u16 lds[36864];   // 72 KB: 3 bufs x 24 KB (V-epilogue reuses first 64 KB)
  int tid = threadIdx.x;
  int l = tid & 63, w = tid >> 6;
  int l15 = l & 15, l4 = l >> 4;
  int wm = w >> 1, wn = w & 1;
  int bid = blockIdx.x;
  int xcd = bid & 7, local = bid >> 3;           // local 0..95
  int mt = xcd*2 + (local >= 48);
  int nt = (local < 48) ? local : local - 48;
  int m0 = mt * 256, n0g = nt * 128;
  int which = nt >> 4;                            // 0=q 1=k 2=v
  int n0 = (nt & 15) * 128;
  const float* bias = which==0 ? bq : which==1 ? bk : bv;
  const float* lB   = which==0 ? lBq : which==1 ? lBk : lBv;
  const float* xs   = xa + which*32768;

  f32x4 acc[8][4];
  #pragma unroll
  for (int mr=0; mr<8; mr++)
    #pragma unroll
    for (int nr=0; nr<4; nr++) acc[mr][nr] = (f32x4){0.f,0.f,0.f,0.f};

  gemm_core_v7(A + (size_t)m0*2048, W + (size_t)n0g*2048, lds, tid, acc);

  float bvv[4]; float4 lb0[4], lb1[4];
  #pragma unroll
  for (int nr=0; nr<4; nr++){
    int col = n0 + wn*64 + nr*16 + l15;
    bvv[nr] = bias[col];
    lb0[nr] = *(const float4*)(lB + col*8);
    lb1[nr] = *(const float4*)(lB + col*8 + 4);
  }

  if (which == 2){
    // ---- V: transpose through LDS, write Vt[bh][d][s] with attn kv-swizzle ----
    __syncthreads();
    char* L = (char*)lds;
    #pragma unroll
    for (int mr=0; mr<8; mr++){
      float vv[4][4];   // [nr][j]
      #pragma unroll
      for (int j=0; j<4; j++){
        int r = m0 + wm*128 + mr*16 + l4*4 + j;
        float4 xv0 = *(const float4*)(xs + (size_t)r*8);
        float4 xv1 = *(const float4*)(xs + (size_t)r*8 + 4);
        #pragma unroll
        for (int nr=0; nr<4; nr++)
          vv[nr][j] = acc[mr][nr][j] + bvv[nr] + LORA_SCALE * (
              xv0.x*lb0[nr].x + xv0.y*lb0[nr].y + xv0.z*lb0[nr].z + xv0.w*lb0[nr].w +
              xv1.x*lb1[nr].x + xv1.y*lb1[nr].y + xv1.z*lb1[nr].z + xv1.w*lb1[nr].w);
      }
      int s_ = wm*128 + mr*16 + l4*4;
      #pragma unroll
      for (int nr=0; nr<4; nr++){
        int d = wn*64 + nr*16 + l15;
        uint2 pk = {cvt_pk_bf16(vv[nr][0], vv[nr][1]), cvt_pk_bf16(vv[nr][2], vv[nr][3])};
        *(uint2*)(L + d*512 + ((s_*2) ^ ((d & 31) << 4))) = pk;
      }
    }
    __syncthreads();
    int bq_ = m0 >> 11, s0 = m0 & 2047, h = n0 >> 7;
    u16* vt = Vtb + ((size_t)((bq_*16 + h)*128)) * 2048;
    #pragma unroll
    for (int i=0; i<16; ++i){
      int flat = i*4096 + tid*16;
      int d = flat >> 9, s2 = flat & 511;
      uint4 val = *(const uint4*)(L + d*512 + (s2 ^ ((d & 31) << 4)));
      int sa = s0 + (s2 >> 1);
      *(uint4*)(vt + (size_t)d*2048 + (sa & ~63) + ((sa & 63) ^ ((d & 7) << 3))) = val;
    }
    return;
  }

  // ---- Q/K: swizzled bf16 store ----
  u16* outp = (which == 0) ? Qb : Kb;
  float oscale = (which == 0) ? QSCALE*LOG2E : 1.0f;
  #pragma unroll
  for (int mr=0; mr<8; mr++)
    #pragma unroll
    for (int j=0; j<4; j++){
      int r = m0 + wm*128 + mr*16 + l4*4 + j;
      float4 xv0 = *(const float4*)(xs + (size_t)r*8);
      float4 xv1 = *(const float4*)(xs + (size_t)r*8 + 4);
      #pragma unroll
      for (int nr=0; nr<4; nr++){
        int col = n0 + wn*64 + nr*16 + l15;
        float v = acc[mr][nr][j] + bvv[nr] + LORA_SCALE * (
            xv0.x*lb0[nr].x + xv0.y*lb0[nr].y + xv0.z*lb0[nr].z + xv0.w*lb0[nr].w +
            xv1.x*lb1[nr].x + xv1.y*lb1[nr].y + xv1.z*lb1[nr].z + xv1.w*lb1[nr].w);
        v *= oscale;
        int cs = col ^ ((r & 7) << 3);
        outp[(size_t)r*2048 + cs] = f2bf(v);
      }
    }
}

// ---------------- O projection GEMM (256x128 tiles, 256 blocks, fp32 out) ----------------
__global__ __launch_bounds__(256, 2) void gemm_o(
    const u16* __restrict__ A, const u16* __restrict__ W,
    const float* __restrict__ bias, const float* __restrict__ lB,
    const float* __restrict__ xa, float* __restrict__ outp){
  __shared__ u16 lds[36864];   // 72 KB
  int tid = threadIdx.x;
  int l = tid & 63, w = tid >> 6;
  int l15 = l & 15, l4 = l >> 4;
  int wm = w >> 1, wn = w & 1;
  int bid = blockIdx.x;
  int xcd = bid & 7, local = bid >> 3;           // local 0..31
  int mt = xcd*2 + (local >= 16);
  int nt = local & 15;
  int m0 = mt * 256, n0 = nt * 128;

  f32x4 acc[8][4];
  #pragma unroll
  for (int mr=0; mr<8; mr++)
    #pragma unroll
    for (int nr=0; nr<4; nr++) acc[mr][nr] = (f32x4){0.f,0.f,0.f,0.f};

  gemm_core_v7(A + (size_t)m0*2048, W + (size_t)n0*2048, lds, tid, acc);

  float bv[4]; float4 lb0[4], lb1[4];
  #pragma unroll
  for (int nr=0; nr<4; nr++){
    int col = n0 + wn*64 + nr*16 + l15;
    bv[nr] = bias[col];
    lb0[nr] = *(const float4*)(lB + col*8);
    lb1[nr] = *(const float4*)(lB + col*8 + 4);
  }
  #pragma unroll
  for (int mr=0; mr<8; mr++)
    #pragma unroll
    for (int j=0; j<4; j++){
      int r = m0 + wm*128 + mr*16 + l4*4 + j;
      float4 xv0 = *(const float4*)(xa + (size_t)r*8);
      float4 xv1 = *(const float4*)(xa + (size_t)r*8 + 4);
      #pragma unroll
      for (int nr=0; nr<4; nr++){
        int col = n0 + wn*64 + nr*16 + l15;
        float v = acc[mr][nr][j] + bv[nr] + LORA_SCALE * (
            xv0.x*lb0[nr].x + xv0.y*lb0[nr].y + xv0.z*lb0[nr].z + xv0.w*lb0[nr].w +
            xv1.x*lb1[nr].x + xv1.y*lb1[nr].y + xv1.z*lb1[nr].z + xv1.w*lb1[nr].w);
        outp[(size_t)r*2048 + col] = v;
      }
    }
}

// ---------------- flash attention: QBLK=128, KVBLK=64, 4 waves x 32 q-rows ----------------
// Epilogue additionally accumulates xa_o = ctx @ Ao^T partials (this head's 128 cols)
// via fp32 global atomicAdd -> replaces the standalone lora_xa kernel.
__global__ __launch_bounds__(256, 2) void attn_kernel(
    const u16* __restrict__ Q, const u16* __restrict__ K,
    const u16* __restrict__ Vt, u16* __restrict__ ctx,
    const float* __restrict__ Ao, float* __restrict__ xao){
  __shared__ u16 buf[2][16384];  // per buffer: K [64][128] (8192 u16) then V [128][64]
  __shared__ u16 Psh[4*32*64];   // 16 KB: per-wave P [32 q][64 kv], XOR-swizzled
  int tid = threadIdx.x, w = tid >> 6, lane = tid & 63;
  int l15 = lane & 15, l4 = lane >> 4;
  int lin = blockIdx.x;
  int virt = (lin & 7) * 64 + (lin >> 3);
  int qt = virt & 15, bh = virt >> 4;
  int b = bh >> 4, h = bh & 15;
  const u16* Qg = Q + (size_t)(b*2048 + qt*128) * 2048 + h*128;
  const u16* Kg = K + (size_t)(b*2048) * 2048 + h*128;
  const u16* Vg = Vt + (size_t)bh * 128 * 2048;

  // prologue: Q -> buf[1], kv-tile 0 -> buf[0]
  #pragma unroll
  for (int i=0; i<8; ++i){
    int e = (i*256 + tid) * 8;
    int r = e >> 7, cc = e & 127;
    gload16(Qg + (size_t)r*2048 + cc, (char*)buf[1] + i*4096 + w*1024);
  }
  #pragma unroll
  for (int i=0; i<4; ++i){
    int e = (i*256 + tid) * 8;
    int r = e >> 7, cc = e & 127;
    gload16(Kg + (size_t)r*2048 + cc, (char*)buf[0] + i*4096 + w*1024);
    int dd = e >> 6, c2 = e & 63;
    gload16(Vg + (size_t)dd*2048 + c2, (char*)buf[0] + 16384 + i*4096 + w*1024);
  }
  __syncthreads();   // drains vmcnt

  bf16x8 qf[2][4];   // Q rows (pre-scaled by log2e/sqrt(dk)); used as B operand
  #pragma unroll
  for (int mi=0; mi<2; mi++){
    int r = w*32 + mi*16 + l15;
    #pragma unroll
    for (int kb=0; kb<4; kb++){
      int cc = (kb*32 + l4*8) ^ ((r & 7) << 3);
      qf[mi][kb] = *(const bf16x8*)(buf[1] + r*128 + cc);
    }
  }
  __syncthreads();   // all waves done with Q region before it becomes buffer 1

  f32x4 ctxa[2][8];
  #pragma unroll
  for (int mi=0; mi<2; mi++)
    #pragma unroll
    for (int nd=0; nd<8; nd++) ctxa[mi][nd] = (f32x4){0.f,0.f,0.f,0.f};
  float mrun[2] = {-3.0e38f, -3.0e38f};
  float lrun[2] = {0.f, 0.f};

  char* PwB = (char*)(Psh + w * (32*64));
  int psw = (l15 & 7) << 4;

  for (int t = 0; t < 32; ++t){
    int cur = t & 1;
    const u16* Kc = buf[cur];
    const u16* Vc = buf[cur] + 8192;
    if (t + 1 < 32){
      int kvn = (t + 1) * 64;
      char* bn = (char*)buf[cur ^ 1];
      #pragma unroll
      for (int i=0; i<4; ++i){
        int e = (i*256 + tid) * 8;
        int r = e >> 7, cc = e & 127;
        gload16(Kg + (size_t)(kvn + r)*2048 + cc, bn + i*4096 + w*1024);
        int dd = e >> 6, c2 = e & 63;
        gload16(Vg + (size_t)dd*2048 + kvn + c2, bn + 16384 + i*4096 + w*1024);
      }
    }
    // S^T = mfma(K, Q)
    f32x4 s[2][4];
    #pragma unroll
    for (int mi=0; mi<2; mi++)
      #pragma unroll
      for (int ni=0; ni<4; ni++) s[mi][ni] = (f32x4){0.f,0.f,0.f,0.f};
    __builtin_amdgcn_s_setprio(1);
    #pragma unroll
    for (int kb=0; kb<4; kb++){
      #pragma unroll
      for (int ni=0; ni<4; ni++){
        int r = ni*16 + l15;
        int cc = (kb*32 + l4*8) ^ ((r & 7) << 3);
        bf16x8 kf = *(const bf16x8*)(Kc + r*128 + cc);
        s[0][ni] = __builtin_amdgcn_mfma_f32_16x16x32_bf16(kf, qf[0][kb], s[0][ni], 0, 0, 0);
        s[1][ni] = __builtin_amdgcn_mfma_f32_16x16x32_bf16(kf, qf[1][kb], s[1][ni], 0, 0, 0);
      }
    }
    __builtin_amdgcn_s_setprio(0);
    float pm[2];
    #pragma unroll
    for (int mi=0; mi<2; mi++){
      float v = s[mi][0][0];
      #pragma unroll
      for (int ni=0; ni<4; ni++)
        #pragma unroll
        for (int j=0; j<4; j++) v = fmaxf(v, s[mi][ni][j]);
      v = fmaxf(v, __shfl_xor(v, 16));
      v = fmaxf(v, __shfl_xor(v, 32));
      pm[mi] = v;
    }
    bool need = (pm[0] > mrun[0] + RESCALE_THR) || (pm[1] > mrun[1] + RESCALE_THR);
    if (__any(need)){
      #pragma unroll
      for (int mi=0; mi<2; mi++){
        float mnew = fmaxf(mrun[mi], pm[mi]);
        float cr = exp2f(mrun[mi] - mnew);
        lrun[mi] *= cr;
        mrun[mi] = mnew;
        #pragma unroll
        for (int nd=0; nd<8; nd++) ctxa[mi][nd] *= cr;
      }
    }
    #pragma unroll
    for (int mi=0; mi<2; mi++){
      float ps = 0.f;
      #pragma unroll
      for (int ni=0; ni<4; ni++){
        float p0 = exp2f(s[mi][ni][0] - mrun[mi]);
        float p1 = exp2f(s[mi][ni][1] - mrun[mi]);
        float p2 = exp2f(s[mi][ni][2] - mrun[mi]);
        float p3 = exp2f(s[mi][ni][3] - mrun[mi]);
        ps += (p0 + p1) + (p2 + p3);
        uint2 pk = {cvt_pk_bf16(p0, p1), cvt_pk_bf16(p2, p3)};
        *(uint2*)(PwB + (mi*16 + l15)*128 + ((ni*32 + l4*8) ^ psw)) = pk;
      }
      ps += __shfl_xor(ps, 16);
      ps += __shfl_xor(ps, 32);
      lrun[mi] += ps;
    }
    bf16x8 pb[2][2];
    #pragma unroll
    for (int mi=0; mi<2; mi++)
      #pragma unroll
      for (int kvb=0; kvb<2; kvb++)
        pb[mi][kvb] = *(const bf16x8*)(PwB + (mi*16 + l15)*128 + ((kvb*64 + l4*16) ^ psw));
    __builtin_amdgcn_s_setprio(1);
    #pragma unroll
    for (int nd=0; nd<8; nd++){
      int dd = nd*16 + l15;
      int sw = (dd & 7) << 3;
      #pragma unroll
      for (int kvb=0; kvb<2; kvb++){
        bf16x8 vf = *(const bf16x8*)(Vc + dd*64 + ((kvb*32 + l4*8) ^ sw));
        ctxa[0][nd] = __builtin_amdgcn_mfma_f32_16x16x32_bf16(vf, pb[0][kvb], ctxa[0][nd], 0, 0, 0);
        ctxa[1][nd] = __builtin_amdgcn_mfma_f32_16x16x32_bf16(vf, pb[1][kvb], ctxa[1][nd], 0, 0, 0);
      }
    }
    __builtin_amdgcn_s_setprio(0);
    __syncthreads();
  }
  // epilogue: normalize; write ctx (LDS transpose, coalesced); accumulate xa_o partials.
  char* OwB = (char*)buf[0] + w*8192;
  const float* AoH = Ao + h*128;   // Ao[8][2048], this head's 128-col slice
  #pragma unroll
  for (int mi=0; mi<2; mi++){
    float inv = 1.0f / lrun[mi];
    f32x4 cn[8];
    #pragma unroll
    for (int nd=0; nd<8; nd++){
      cn[nd] = ctxa[mi][nd] * inv;
      uint2 pk = {cvt_pk_bf16(cn[nd][0], cn[nd][1]), cvt_pk_bf16(cn[nd][2], cn[nd][3])};
      *(uint2*)(OwB + (mi*16 + l15)*256 + ((nd*32 + l4*8) ^ psw)) = pk;
    }
    // xa_o partial: this lane covers q = mi*16+l15 (32 d-values: nd*16 + l4*4 + j)
    int mglob = b*2048 + qt*128 + w*32 + mi*16 + l15;
    #pragma unroll
    for (int r=0; r<8; r++){
      float a = 0.f;
      #pragma unroll
      for (int nd=0; nd<8; nd++){
        float4 av = *(const float4*)(AoH + r*2048 + nd*16 + l4*4);
        a += cn[nd][0]*av.x + cn[nd][1]*av.y + cn[nd][2]*av.z + cn[nd][3]*av.w;
      }
      a += __shfl_xor(a, 16);
      a += __shfl_xor(a, 32);
      if (lane < 16) atomicAdd(xao + mglob*8 + r, a);
    }
  }
  #pragma unroll
  for (int i=0; i<8; ++i){
    int row = i*4 + l4;
    int colb = l15*16;
    uint4 v = *(const uint4*)(OwB + row*256 + (colb ^ ((row & 7) << 4)));
    int srow = qt*128 + w*32 + row;
    *(uint4*)(ctx + ((size_t)(b*2048 + srow))*2048 + h*128 + colb/2) = v;
  }
}

// ---------------- launcher ----------------
extern "C" void kernel_launch(void* const* d_in, const int* in_sizes, int n_in,
                              void* d_out, int out_size, void* d_ws, size_t ws_size,
                              hipStream_t stream){
  const float* x  = (const float*)d_in[0];
  const float* Wq = (const float*)d_in[1];  const float* bq = (const float*)d_in[2];
  const float* Aq = (const float*)d_in[3];  const float* Bq = (const float*)d_in[4];
  const float* Wk = (const float*)d_in[5];  const float* bk = (const float*)d_in[6];
  const float* Ak = (const float*)d_in[7];  const float* Bk = (const float*)d_in[8];
  const float* Wv = (const float*)d_in[9];  const float* bv = (const float*)d_in[10];
  const float* Av = (const float*)d_in[11]; const float* Bv = (const float*)d_in[12];
  const float* Wo = (const float*)d_in[13]; const float* bo = (const float*)d_in[14];
  const float* Ao = (const float*)d_in[15]; const float* Bo = (const float*)d_in[16];

  char* ws = (char*)d_ws;
  size_t off = 0;
  u16* xbf  = (u16*)(ws + off); off += (size_t)4096*2048*2;          // 16 MB
  u16* wqkv = (u16*)(ws + off); off += (size_t)3*2048*2048*2;        // 24 MB
  u16* wob  = (u16*)(ws + off); off += (size_t)2048*2048*2;          // 8 MB
  float* xa = (float*)(ws + off); off += (size_t)4*32768*4;          // 4 slabs [4096][8]
  u16* Qb  = (u16*)(ws + off); off += (size_t)4096*2048*2;
  u16* Kb  = (u16*)(ws + off); off += (size_t)4096*2048*2;
  u16* Vb  = (u16*)(ws + off); off += (size_t)4096*2048*2;           // ctx buffer
  u16* Vtb = (u16*)(ws + off); off += (size_t)4096*2048*2;
  if (ws_size < off) return;
  float* xao = xa + 98304;

  cvt_lora<<<9217, 256, 0, stream>>>(Wq, Wk, Wv, Wo, wqkv, wob, x, Aq, Ak, Av, xa, xbf, xao);

  gemm_qkv<<<768, 256, 0, stream>>>(xbf, wqkv, bq, bk, bv, Bq, Bk, Bv, xa, Qb, Kb, Vtb);

  attn_kernel<<<512, 256, 0, stream>>>(Qb, Kb, Vtb, Vb, Ao, xao);   // ctx -> Vb, xa_o via atomics

  gemm_o<<<256, 256, 0, stream>>>(Vb, wob, bo, Bo, xao, (float*)d_out);
}